// Round 1
// 1195.134 us; speedup vs baseline: 1.0105x; 1.0105x over previous
//
#include <hip/hip_runtime.h>
#include <hip/hip_bf16.h>
#include <math.h>
#include <stdint.h>

// ---------------------------------------------------------------------------
// GCN 4-layer, bf16 datapath:
//   h = relu( A_w @ (h @ W) + b ) x4, then log_softmax (fp32 out).
//   - dst-CSR built once per call; edges packed u32 (src<<15 | w*32767)
//   - CSR scatter is 2-phase bucket-binned (dst>>8) so the final scatter
//     writes land in ~32KB windows (line-coalesced) instead of random 4B/64B
//   - GEMM: bf16 MFMA 16x16x32, tile 128x64, BK=64, global_load_lds staging
//   - SpMM v2: lane-GROUP per edge (G = D/8 lanes, 16B ushort8 gathers),
//     64/G edges concurrent per wave x U unrolled = 16 edges in flight,
//     cross-group shfl_xor butterfly merge, fused bias+relu; L4 variant
//     additionally fuses log_softmax (writes final fp32 [n,40] directly).
//   - edge_pk is zero-padded by 64 entries so the SpMM inner loop needs no
//     address clamping (tail edges get weight 0; pad gathers row 0).
// ---------------------------------------------------------------------------

#define WAVE 64
#define NBK 512          // scatter buckets (dst >> 8)
#define CHA 8192         // edges per phaseA block
typedef __attribute__((ext_vector_type(8))) short short8;
typedef __attribute__((ext_vector_type(8))) unsigned short ushort8;
typedef __attribute__((ext_vector_type(4))) unsigned int uintx4;
typedef __attribute__((ext_vector_type(4))) float floatx4;

__device__ __forceinline__ void async_copy16(const void* g, void* l) {
    __builtin_amdgcn_global_load_lds(
        (const __attribute__((address_space(1))) void*)g,
        (__attribute__((address_space(3))) void*)l, 16, 0, 0);
}
__device__ __forceinline__ float bf2f(unsigned short u) {
    union { unsigned int i; float f; } x; x.i = ((unsigned int)u) << 16; return x.f;
}

// ---------------- setup conversions ----------------

__global__ __launch_bounds__(256) void convert_x_kernel(const float* __restrict__ in,
                                                        __hip_bfloat16* __restrict__ out,
                                                        long n4) {
    long i = ((long)blockIdx.x * 256 + threadIdx.x);
    if (i >= n4) return;
    const float4 v = *(const float4*)(in + i * 4);
    __hip_bfloat16* o = out + i * 4;
    o[0] = __float2bfloat16(v.x); o[1] = __float2bfloat16(v.y);
    o[2] = __float2bfloat16(v.z); o[3] = __float2bfloat16(v.w);
}

// All weight transposes + bias pad in ONE kernel (launch-gap trim).
// Segments: Wt1 131072 | Wt2 32768 | Wt3 8192 | Wt4 4096 | b4p 64
__global__ __launch_bounds__(256) void prep_weights_kernel(
        const float* __restrict__ W1, const float* __restrict__ W2,
        const float* __restrict__ W3, const float* __restrict__ W4,
        const float* __restrict__ b4,
        __hip_bfloat16* __restrict__ Wt1, __hip_bfloat16* __restrict__ Wt2,
        __hip_bfloat16* __restrict__ Wt3, __hip_bfloat16* __restrict__ Wt4,
        float* __restrict__ b4p) {
    int idx = blockIdx.x * 256 + threadIdx.x;
    if (idx < 131072) {                       // Wt1: K=512 N=256
        int n = idx >> 9, k = idx & 511;
        Wt1[idx] = __float2bfloat16(W1[(size_t)k * 256 + n]);
    } else if (idx < 131072 + 32768) {        // Wt2: K=256 N=128
        int l = idx - 131072;
        int n = l >> 8, k = l & 255;
        Wt2[l] = __float2bfloat16(W2[(size_t)k * 128 + n]);
    } else if (idx < 131072 + 32768 + 8192) { // Wt3: K=128 N=64
        int l = idx - 131072 - 32768;
        int n = l >> 7, k = l & 127;
        Wt3[l] = __float2bfloat16(W3[(size_t)k * 64 + n]);
    } else if (idx < 131072 + 32768 + 8192 + 4096) { // Wt4: K=64 N=40 pad 64
        int l = idx - 131072 - 32768 - 8192;
        int n = l >> 6, k = l & 63;
        float v = (n < 40) ? W4[(size_t)k * 40 + n] : 0.f;
        Wt4[l] = __float2bfloat16(v);
    } else if (idx < 131072 + 32768 + 8192 + 4096 + 64) {
        int l = idx - 131072 - 32768 - 8192 - 4096;
        b4p[l] = (l < 40) ? b4[l] : 0.f;
    }
}

// ---------------- CSR build ----------------

__global__ __launch_bounds__(256) void hist_kernel(const int* __restrict__ dst,
                                                   int nE, int* __restrict__ counts) {
    int i = blockIdx.x * 256 + threadIdx.x;
    if (i < nE) atomicAdd(&counts[dst[i]], 1);
}

__global__ __launch_bounds__(1024) void scan1_kernel(const int* __restrict__ counts,
                                                     int n, int* __restrict__ partial,
                                                     int* __restrict__ bsum) {
    __shared__ int sm[1024];
    int tid = threadIdx.x;
    int i = blockIdx.x * 1024 + tid;
    int x = (i < n) ? counts[i] : 0;
    sm[tid] = x;
    __syncthreads();
    for (int off = 1; off < 1024; off <<= 1) {
        int add = 0;
        if (tid >= off) add = sm[tid - off];
        __syncthreads();
        if (tid >= off) sm[tid] += add;
        __syncthreads();
    }
    int incl = sm[tid];
    if (i < n) partial[i] = incl - x;
    if (tid == 1023) bsum[blockIdx.x] = incl;
}

__global__ __launch_bounds__(1024) void scan2_kernel(const int* __restrict__ bsum,
                                                     int nb, int* __restrict__ boff) {
    __shared__ int sm[1024];
    int tid = threadIdx.x;
    int x = (tid < nb) ? bsum[tid] : 0;
    sm[tid] = x;
    __syncthreads();
    for (int off = 1; off < 1024; off <<= 1) {
        int add = 0;
        if (tid >= off) add = sm[tid - off];
        __syncthreads();
        if (tid >= off) sm[tid] += add;
        __syncthreads();
    }
    if (tid < nb) boff[tid] = sm[tid] - x;
}

// finalize row_ptr; init row_cur and per-bucket cursors gcur[b]=row_ptr[b<<8];
// also zero the 64-entry edge_pk tail pad (SpMM reads past row ends).
__global__ __launch_bounds__(256) void scan3_kernel(int* __restrict__ row_ptr,
                                                    const int* __restrict__ boff,
                                                    int n, int nE,
                                                    int* __restrict__ row_cur,
                                                    int* __restrict__ gcur,
                                                    unsigned int* __restrict__ edge_pk) {
    int i = blockIdx.x * 256 + threadIdx.x;
    if (i < n) {
        int v = row_ptr[i] + boff[i >> 10];
        row_ptr[i] = v;
        row_cur[i] = v;
        if ((i & 255) == 0) gcur[i >> 8] = v;
    }
    if (i == 0) row_ptr[n] = nE;
    if (i < 64) edge_pk[nE + i] = 0u;
}

// Phase A: bucket edges by dst>>8 into E2 staging (u64: .y=dst, .x=src<<15|w15).
// Per-block LDS histogram + one global reservation per (block,bucket); writes
// land as ~16-entry runs per bucket region (line-friendly).
__global__ __launch_bounds__(256) void scatter_phaseA(const int* __restrict__ src,
                                                      const int* __restrict__ dst,
                                                      const float* __restrict__ ew,
                                                      int nE,
                                                      int* __restrict__ gcur,
                                                      uint2* __restrict__ E2) {
    __shared__ int hist[NBK];
    __shared__ int cur[NBK];
    const int t = threadIdx.x;
    const long e0 = (long)blockIdx.x * CHA;
    const int cnt = (int)((nE - e0 < CHA) ? (nE - e0) : CHA);

    for (int i = t; i < NBK; i += 256) hist[i] = 0;
    __syncthreads();
    for (int i = t; i < cnt; i += 256)
        atomicAdd(&hist[dst[e0 + i] >> 8], 1);
    __syncthreads();
    for (int i = t; i < NBK; i += 256) {
        int h = hist[i];
        cur[i] = h ? atomicAdd(&gcur[i], h) : 0;   // global base for this block
    }
    __syncthreads();
    for (int i = t; i < cnt; i += 256) {
        int d = dst[e0 + i];
        unsigned int w15 = (unsigned int)(ew[e0 + i] * 32767.f + 0.5f);
        if (w15 > 32767u) w15 = 32767u;
        int pos = atomicAdd(&cur[d >> 8], 1);      // LDS atomic -> global slot
        E2[pos] = make_uint2(((unsigned int)src[e0 + i] << 15) | w15,
                             (unsigned int)d);
    }
}

// Phase B: exact CSR placement. Each bucket's writes span only ~32KB of
// edge_pk, so the 4B scatters coalesce in L2 instead of costing a line each.
__global__ __launch_bounds__(256) void scatter_phaseB(const uint2* __restrict__ E2,
                                                      int nE,
                                                      int* __restrict__ row_cur,
                                                      unsigned int* __restrict__ edge_pk) {
    int i = blockIdx.x * 256 + threadIdx.x;
    if (i < nE) {
        uint2 e = E2[i];
        int pos = atomicAdd(&row_cur[e.y], 1);
        edge_pk[pos] = e.x;
    }
}

// ---------------- bf16 MFMA GEMM: C[M,Npitch] = A[M,K] @ Wt[Npitch,K]^T -----

__global__ __launch_bounds__(256) void gemm_bf16(const __hip_bfloat16* __restrict__ A,
                                                 const __hip_bfloat16* __restrict__ Wt,
                                                 __hip_bfloat16* __restrict__ C,
                                                 int M, int K, int Npitch) {
    __shared__ __align__(16) __hip_bfloat16 sA[128 * 64];  // [row][k], 128B rows
    __shared__ __align__(16) __hip_bfloat16 sB[64 * 64];   // [n][k],   128B rows
    const int t = threadIdx.x;
    const int lane = t & 63;
    const int w = t >> 6;
    const int wy = w >> 1, wx = w & 1;
    const int quad = lane >> 4;
    const int l16 = lane & 15;
    const int row0 = blockIdx.y * 128;
    const int col0 = blockIdx.x * 64;

    floatx4 acc[4][2];
#pragma unroll
    for (int mt = 0; mt < 4; mt++)
#pragma unroll
        for (int nt = 0; nt < 2; nt++) acc[mt][nt] = 0;

    const int arow = t >> 3;
    const int koff = (t & 7) * 8;

    for (int k0 = 0; k0 < K; k0 += 64) {
#pragma unroll
        for (int r = 0; r < 4; r++) {
            int gm = row0 + r * 32 + arow;
            int gmc = (gm < M) ? gm : 0;
            async_copy16(A + (size_t)gmc * K + k0 + koff,
                         (char*)sA + r * 4096 + t * 16);
        }
#pragma unroll
        for (int r = 0; r < 2; r++) {
            int n = r * 32 + arow;
            async_copy16(Wt + (size_t)(col0 + n) * K + k0 + koff,
                         (char*)sB + r * 4096 + t * 16);
        }
        __syncthreads();

        short8 af[4][2], bfr[2][2];
#pragma unroll
        for (int mt = 0; mt < 4; mt++)
#pragma unroll
            for (int kk = 0; kk < 2; kk++)
                af[mt][kk] = *(const short8*)((const char*)sA +
                             (wy * 64 + mt * 16 + l16) * 128 + kk * 64 + quad * 16);
#pragma unroll
        for (int nt = 0; nt < 2; nt++)
#pragma unroll
            for (int kk = 0; kk < 2; kk++)
                bfr[nt][kk] = *(const short8*)((const char*)sB +
                              (wx * 32 + nt * 16 + l16) * 128 + kk * 64 + quad * 16);
#pragma unroll
        for (int kk = 0; kk < 2; kk++)
#pragma unroll
            for (int mt = 0; mt < 4; mt++)
#pragma unroll
                for (int nt = 0; nt < 2; nt++)
                    acc[mt][nt] = __builtin_amdgcn_mfma_f32_16x16x32_bf16(
                        af[mt][kk], bfr[nt][kk], acc[mt][nt], 0, 0, 0);
        __syncthreads();
    }

#pragma unroll
    for (int mt = 0; mt < 4; mt++) {
#pragma unroll
        for (int nt = 0; nt < 2; nt++) {
            int gn = col0 + wx * 32 + nt * 16 + l16;
            int gmb = row0 + wy * 64 + mt * 16 + quad * 4;
#pragma unroll
            for (int r = 0; r < 4; r++) {
                int gm = gmb + r;
                if (gm < M)
                    C[(size_t)gm * Npitch + gn] = __float2bfloat16(acc[mt][nt][r]);
            }
        }
    }
}

// ---------------- SpMM (CSR by dst) + bias + relu, bf16 gathers -------------
// v2: one wave per dst node; lanes split into 64/G groups of G lanes; each
// group owns one edge at a time and gathers its support row as G x 16B
// (ushort8) loads; U rounds unrolled => (64/G)*U edges in flight per wave.
// After the row, a shfl_xor butterfly over offsets {G..32} merges the group
// partials (leaves every lane with the full sum for its 8 columns).
// FINAL=true additionally fuses log_softmax over the 40 real classes
// (support pitch 64; pad cols are exactly zero) and writes fp32 [n,40].

template <int D, int G, int U, bool FINAL, typename OT>
__global__ __launch_bounds__(256) void spmm_bias_relu(const int* __restrict__ row_ptr,
                                                      const unsigned int* __restrict__ edge_pk,
                                                      const __hip_bfloat16* __restrict__ support,
                                                      const float* __restrict__ bias,
                                                      OT* __restrict__ out,
                                                      int n_nodes) {
    constexpr int NG = 64 / G;           // edge groups per wave
    constexpr int CH = NG * U;           // edges consumed per iteration
    int node = blockIdx.x * (256 / WAVE) + (threadIdx.x >> 6);
    if (node >= n_nodes) return;
    node = __builtin_amdgcn_readfirstlane(node);
    const int lane = threadIdx.x & 63;
    const int g = lane / G;              // edge-group id
    const int t = lane & (G - 1);        // lane-in-group: owns cols [t*8, t*8+8)
    int e = row_ptr[node];
    const int end = row_ptr[node + 1];
    const unsigned short* sup = (const unsigned short*)support + t * 8;

    float acc[8];
#pragma unroll
    for (int i = 0; i < 8; i++) acc[i] = 0.f;

    while (e < end) {
        const int base = e + g * U;      // this group's contiguous edge chunk
        unsigned int pk[U];
#pragma unroll
        for (int u = 0; u < U; u++) pk[u] = edge_pk[base + u];  // pad-safe
        ushort8 v[U];
#pragma unroll
        for (int u = 0; u < U; u++)
            v[u] = *(const ushort8*)(sup + (size_t)(pk[u] >> 15) * D);
#pragma unroll
        for (int u = 0; u < U; u++) {
            float wq = (float)(pk[u] & 0x7fffu) * (1.f / 32767.f);
            float wt = (base + u < end) ? wq : 0.f;   // tail contributes 0
#pragma unroll
            for (int i = 0; i < 8; i++) acc[i] += bf2f(v[u][i]) * wt;
        }
        e += CH;
    }

    // merge group partials: butterfly over group-id bits (all lanes end with
    // the full sum for their column slice)
#pragma unroll
    for (int off = G; off < 64; off <<= 1)
#pragma unroll
        for (int i = 0; i < 8; i++) acc[i] += __shfl_xor(acc[i], off);

    if (!FINAL) {
        ushort8 o;
#pragma unroll
        for (int i = 0; i < 8; i++) {
            float r = acc[i] + bias[t * 8 + i];
            r = r > 0.f ? r : 0.f;
            __hip_bfloat16 b = __float2bfloat16(r);
            o[i] = *(unsigned short*)&b;
        }
        if (lane < G) {
            union { ushort8 s; uintx4 u; } cvt; cvt.s = o;
            __builtin_nontemporal_store(cvt.u,
                (uintx4*)((unsigned short*)out + (size_t)node * D + t * 8));
        }
    } else {
        // D==64 pitch, 40 real classes; fused log_softmax
        float r[8];
#pragma unroll
        for (int i = 0; i < 8; i++) {
            float x = acc[i] + bias[t * 8 + i];
            r[i] = x > 0.f ? x : 0.f;
        }
        float m = -INFINITY;
#pragma unroll
        for (int i = 0; i < 8; i++)
            if (t * 8 + i < 40) m = fmaxf(m, r[i]);
#pragma unroll
        for (int off = 1; off < G; off <<= 1) m = fmaxf(m, __shfl_xor(m, off));
        float s = 0.f;
#pragma unroll
        for (int i = 0; i < 8; i++)
            if (t * 8 + i < 40) s += __expf(r[i] - m);
#pragma unroll
        for (int off = 1; off < G; off <<= 1) s += __shfl_xor(s, off);
        const float lse = __logf(s);
        if (lane < 5) {                 // lanes 0..4 cover cols 0..39
            float* op = (float*)out + (size_t)node * 40 + lane * 8;
#pragma unroll
            for (int i = 0; i < 8; i++) op[i] = r[i] - m - lse;
        }
    }
}

// ---------------- launch ----------------------------------------------------

extern "C" void kernel_launch(void* const* d_in, const int* in_sizes, int n_in,
                              void* d_out, int out_size, void* d_ws, size_t ws_size,
                              hipStream_t stream) {
    const float* x    = (const float*)d_in[0];
    const int*   esrc = (const int*)d_in[1];
    const int*   edst = (const int*)d_in[2];
    const float* ew   = (const float*)d_in[3];
    const float* Wm[4] = {(const float*)d_in[4], (const float*)d_in[6],
                          (const float*)d_in[8], (const float*)d_in[10]};
    const float* bm[4] = {(const float*)d_in[5], (const float*)d_in[7],
                          (const float*)d_in[9], (const float*)d_in[11]};
    const int NFEAT = 512;
    const int n_nodes = in_sizes[0] / NFEAT;
    const int n_edges = in_sizes[1];
    float* out = (float*)d_out;

    // --- workspace carve ---
    char* wsp = (char*)d_ws;
    size_t off = 0;
    auto alloc = [&](size_t bytes) -> void* {
        void* p = wsp + off;
        off += (bytes + 255) & ~(size_t)255;
        return p;
    };
    __hip_bfloat16* Xb = (__hip_bfloat16*)alloc((size_t)n_nodes * 512 * sizeof(__hip_bfloat16));
    __hip_bfloat16* Sb = (__hip_bfloat16*)alloc((size_t)n_nodes * 256 * sizeof(__hip_bfloat16));
    __hip_bfloat16* Hb = (__hip_bfloat16*)alloc((size_t)n_nodes * 256 * sizeof(__hip_bfloat16));
    __hip_bfloat16* Wt1 = (__hip_bfloat16*)alloc(256 * 512 * sizeof(__hip_bfloat16));
    __hip_bfloat16* Wt2 = (__hip_bfloat16*)alloc(128 * 256 * sizeof(__hip_bfloat16));
    __hip_bfloat16* Wt3 = (__hip_bfloat16*)alloc(64 * 128 * sizeof(__hip_bfloat16));
    __hip_bfloat16* Wt4 = (__hip_bfloat16*)alloc(64 * 64 * sizeof(__hip_bfloat16));
    float* b4p     = (float*)alloc(64 * sizeof(float));
    int*   counts  = (int*)alloc((size_t)n_nodes * sizeof(int));
    int*   row_ptr = (int*)alloc(((size_t)n_nodes + 1) * sizeof(int));
    int*   row_cur = (int*)alloc((size_t)n_nodes * sizeof(int));
    int*   bsum    = (int*)alloc(1024 * sizeof(int));
    int*   boff    = (int*)alloc(1024 * sizeof(int));
    int*   gcur    = (int*)alloc(NBK * sizeof(int));
    unsigned int* edge_pk = (unsigned int*)alloc(((size_t)n_edges + 64) * sizeof(unsigned int));
    // E2 staging (8B/edge) aliases Hb: Hb is first written by L1 SpMM, which
    // runs after phaseB completes (same stream) -> safe.
    uint2* E2 = (uint2*)Hb;
    (void)ws_size;

    // --- conversions ---
    long n4 = (long)n_nodes * 512 / 4;
    convert_x_kernel<<<(int)((n4 + 255) / 256), 256, 0, stream>>>(x, Xb, n4);
    prep_weights_kernel<<<(131072 + 32768 + 8192 + 4096 + 64 + 255) / 256, 256, 0, stream>>>(
        Wm[0], Wm[1], Wm[2], Wm[3], bm[3], Wt1, Wt2, Wt3, Wt4, b4p);

    // --- CSR build ---
    hipMemsetAsync(counts, 0, (size_t)n_nodes * sizeof(int), stream);
    hist_kernel<<<(n_edges + 255) / 256, 256, 0, stream>>>(edst, n_edges, counts);
    int nb = (n_nodes + 1023) / 1024;
    scan1_kernel<<<nb, 1024, 0, stream>>>(counts, n_nodes, row_ptr, bsum);
    scan2_kernel<<<1, 1024, 0, stream>>>(bsum, nb, boff);
    scan3_kernel<<<(n_nodes + 255) / 256, 256, 0, stream>>>(row_ptr, boff, n_nodes,
                                                            n_edges, row_cur, gcur,
                                                            edge_pk);
    scatter_phaseA<<<(n_edges + CHA - 1) / CHA, 256, 0, stream>>>(esrc, edst, ew,
                                                                  n_edges, gcur, E2);
    scatter_phaseB<<<(n_edges + 255) / 256, 256, 0, stream>>>(E2, n_edges,
                                                              row_cur, edge_pk);

    // --- layers ---
    auto gemm = [&](const __hip_bfloat16* A, const __hip_bfloat16* Wt,
                    __hip_bfloat16* C, int K, int Npitch) {
        dim3 grid(Npitch / 64, (n_nodes + 127) / 128);
        gemm_bf16<<<grid, 256, 0, stream>>>(A, Wt, C, n_nodes, K, Npitch);
    };
    int spmm_blocks = (n_nodes + 3) / 4;

    // L1: 512 -> 256
    gemm(Xb, Wt1, Sb, 512, 256);
    spmm_bias_relu<256, 32, 8, false, __hip_bfloat16><<<spmm_blocks, 256, 0, stream>>>(
        row_ptr, edge_pk, Sb, bm[0], Hb, n_nodes);
    // L2: 256 -> 128
    gemm(Hb, Wt2, Sb, 256, 128);
    spmm_bias_relu<128, 16, 4, false, __hip_bfloat16><<<spmm_blocks, 256, 0, stream>>>(
        row_ptr, edge_pk, Sb, bm[1], Hb, n_nodes);
    // L3: 128 -> 64
    gemm(Hb, Wt3, Sb, 128, 64);
    spmm_bias_relu<64, 8, 2, false, __hip_bfloat16><<<spmm_blocks, 256, 0, stream>>>(
        row_ptr, edge_pk, Sb, bm[2], Hb, n_nodes);
    // L4: 64 -> 40 (N padded to 64; padded support cols/bias are zero)
    // fused log_softmax -> writes final fp32 [n,40] directly
    gemm(Hb, Wt4, Sb, 64, 64);
    spmm_bias_relu<64, 8, 2, true, float><<<spmm_blocks, 256, 0, stream>>>(
        row_ptr, edge_pk, Sb, b4p, out, n_nodes);
}

// Round 2
// 1133.435 us; speedup vs baseline: 1.0655x; 1.0544x over previous
//
#include <hip/hip_runtime.h>
#include <hip/hip_bf16.h>
#include <math.h>
#include <stdint.h>

// ---------------------------------------------------------------------------
// GCN 4-layer, bf16 datapath:
//   h = relu( A_w @ (h @ W) + b ) x4, then log_softmax (fp32 out).
//   - dst-CSR built once per call; edges packed u32 (src<<15 | w*32767)
//   - CSR scatter is 2-phase bucket-binned (dst>>8) so the final scatter
//     writes land in ~32KB windows (line-coalesced) instead of random 4B/64B
//   - GEMM: bf16 MFMA 16x16x32, tile 128x64, BK=64, global_load_lds staging
//   - SpMM v3: lane-GROUP per edge (G = D/8 lanes, 16B ushort8 gathers),
//     edge index CLAMPED inside the row (tail re-reads the row's last edge,
//     which is L1/L2-resident -> zero extra fetch; weight forced to 0).
//     SpMM duration is fetch-bound at ~3.55 TB/s, so fetch bytes == time.
//     L4 variant fuses log_softmax (writes final fp32 [n,40] directly).
// ---------------------------------------------------------------------------

#define WAVE 64
#define NBK 512          // scatter buckets (dst >> 8)
#define CHA 8192         // edges per phaseA block
typedef __attribute__((ext_vector_type(8))) short short8;
typedef __attribute__((ext_vector_type(8))) unsigned short ushort8;
typedef __attribute__((ext_vector_type(4))) unsigned int uintx4;
typedef __attribute__((ext_vector_type(4))) float floatx4;

__device__ __forceinline__ void async_copy16(const void* g, void* l) {
    __builtin_amdgcn_global_load_lds(
        (const __attribute__((address_space(1))) void*)g,
        (__attribute__((address_space(3))) void*)l, 16, 0, 0);
}
__device__ __forceinline__ float bf2f(unsigned short u) {
    union { unsigned int i; float f; } x; x.i = ((unsigned int)u) << 16; return x.f;
}

// ---------------- setup conversions ----------------

__global__ __launch_bounds__(256) void convert_x_kernel(const float* __restrict__ in,
                                                        __hip_bfloat16* __restrict__ out,
                                                        long n4) {
    long i = ((long)blockIdx.x * 256 + threadIdx.x);
    if (i >= n4) return;
    const float4 v = *(const float4*)(in + i * 4);
    __hip_bfloat16* o = out + i * 4;
    o[0] = __float2bfloat16(v.x); o[1] = __float2bfloat16(v.y);
    o[2] = __float2bfloat16(v.z); o[3] = __float2bfloat16(v.w);
}

// All weight transposes + bias pad in ONE kernel (launch-gap trim).
// Segments: Wt1 131072 | Wt2 32768 | Wt3 8192 | Wt4 4096 | b4p 64
__global__ __launch_bounds__(256) void prep_weights_kernel(
        const float* __restrict__ W1, const float* __restrict__ W2,
        const float* __restrict__ W3, const float* __restrict__ W4,
        const float* __restrict__ b4,
        __hip_bfloat16* __restrict__ Wt1, __hip_bfloat16* __restrict__ Wt2,
        __hip_bfloat16* __restrict__ Wt3, __hip_bfloat16* __restrict__ Wt4,
        float* __restrict__ b4p) {
    int idx = blockIdx.x * 256 + threadIdx.x;
    if (idx < 131072) {                       // Wt1: K=512 N=256
        int n = idx >> 9, k = idx & 511;
        Wt1[idx] = __float2bfloat16(W1[(size_t)k * 256 + n]);
    } else if (idx < 131072 + 32768) {        // Wt2: K=256 N=128
        int l = idx - 131072;
        int n = l >> 8, k = l & 255;
        Wt2[l] = __float2bfloat16(W2[(size_t)k * 128 + n]);
    } else if (idx < 131072 + 32768 + 8192) { // Wt3: K=128 N=64
        int l = idx - 131072 - 32768;
        int n = l >> 7, k = l & 127;
        Wt3[l] = __float2bfloat16(W3[(size_t)k * 64 + n]);
    } else if (idx < 131072 + 32768 + 8192 + 4096) { // Wt4: K=64 N=40 pad 64
        int l = idx - 131072 - 32768 - 8192;
        int n = l >> 6, k = l & 63;
        float v = (n < 40) ? W4[(size_t)k * 40 + n] : 0.f;
        Wt4[l] = __float2bfloat16(v);
    } else if (idx < 131072 + 32768 + 8192 + 4096 + 64) {
        int l = idx - 131072 - 32768 - 8192 - 4096;
        b4p[l] = (l < 40) ? b4[l] : 0.f;
    }
}

// ---------------- CSR build ----------------

__global__ __launch_bounds__(256) void hist_kernel(const int* __restrict__ dst,
                                                   int nE, int* __restrict__ counts) {
    int i = blockIdx.x * 256 + threadIdx.x;
    if (i < nE) atomicAdd(&counts[dst[i]], 1);
}

__global__ __launch_bounds__(1024) void scan1_kernel(const int* __restrict__ counts,
                                                     int n, int* __restrict__ partial,
                                                     int* __restrict__ bsum) {
    __shared__ int sm[1024];
    int tid = threadIdx.x;
    int i = blockIdx.x * 1024 + tid;
    int x = (i < n) ? counts[i] : 0;
    sm[tid] = x;
    __syncthreads();
    for (int off = 1; off < 1024; off <<= 1) {
        int add = 0;
        if (tid >= off) add = sm[tid - off];
        __syncthreads();
        if (tid >= off) sm[tid] += add;
        __syncthreads();
    }
    int incl = sm[tid];
    if (i < n) partial[i] = incl - x;
    if (tid == 1023) bsum[blockIdx.x] = incl;
}

__global__ __launch_bounds__(1024) void scan2_kernel(const int* __restrict__ bsum,
                                                     int nb, int* __restrict__ boff) {
    __shared__ int sm[1024];
    int tid = threadIdx.x;
    int x = (tid < nb) ? bsum[tid] : 0;
    sm[tid] = x;
    __syncthreads();
    for (int off = 1; off < 1024; off <<= 1) {
        int add = 0;
        if (tid >= off) add = sm[tid - off];
        __syncthreads();
        if (tid >= off) sm[tid] += add;
        __syncthreads();
    }
    if (tid < nb) boff[tid] = sm[tid] - x;
}

// finalize row_ptr; init row_cur and per-bucket cursors gcur[b]=row_ptr[b<<8]
__global__ __launch_bounds__(256) void scan3_kernel(int* __restrict__ row_ptr,
                                                    const int* __restrict__ boff,
                                                    int n, int nE,
                                                    int* __restrict__ row_cur,
                                                    int* __restrict__ gcur) {
    int i = blockIdx.x * 256 + threadIdx.x;
    if (i < n) {
        int v = row_ptr[i] + boff[i >> 10];
        row_ptr[i] = v;
        row_cur[i] = v;
        if ((i & 255) == 0) gcur[i >> 8] = v;
    }
    if (i == 0) row_ptr[n] = nE;
}

// Phase A: bucket edges by dst>>8 into E2 staging (u64: .y=dst, .x=src<<15|w15).
// Per-block LDS histogram + one global reservation per (block,bucket); writes
// land as ~16-entry runs per bucket region (line-friendly).
__global__ __launch_bounds__(256) void scatter_phaseA(const int* __restrict__ src,
                                                      const int* __restrict__ dst,
                                                      const float* __restrict__ ew,
                                                      int nE,
                                                      int* __restrict__ gcur,
                                                      uint2* __restrict__ E2) {
    __shared__ int hist[NBK];
    __shared__ int cur[NBK];
    const int t = threadIdx.x;
    const long e0 = (long)blockIdx.x * CHA;
    const int cnt = (int)((nE - e0 < CHA) ? (nE - e0) : CHA);

    for (int i = t; i < NBK; i += 256) hist[i] = 0;
    __syncthreads();
    for (int i = t; i < cnt; i += 256)
        atomicAdd(&hist[dst[e0 + i] >> 8], 1);
    __syncthreads();
    for (int i = t; i < NBK; i += 256) {
        int h = hist[i];
        cur[i] = h ? atomicAdd(&gcur[i], h) : 0;   // global base for this block
    }
    __syncthreads();
    for (int i = t; i < cnt; i += 256) {
        int d = dst[e0 + i];
        unsigned int w15 = (unsigned int)(ew[e0 + i] * 32767.f + 0.5f);
        if (w15 > 32767u) w15 = 32767u;
        int pos = atomicAdd(&cur[d >> 8], 1);      // LDS atomic -> global slot
        E2[pos] = make_uint2(((unsigned int)src[e0 + i] << 15) | w15,
                             (unsigned int)d);
    }
}

// Phase B: exact CSR placement. Each bucket's writes span only ~32KB of
// edge_pk, so the 4B scatters coalesce in L2 instead of costing a line each.
__global__ __launch_bounds__(256) void scatter_phaseB(const uint2* __restrict__ E2,
                                                      int nE,
                                                      int* __restrict__ row_cur,
                                                      unsigned int* __restrict__ edge_pk) {
    int i = blockIdx.x * 256 + threadIdx.x;
    if (i < nE) {
        uint2 e = E2[i];
        int pos = atomicAdd(&row_cur[e.y], 1);
        edge_pk[pos] = e.x;
    }
}

// ---------------- bf16 MFMA GEMM: C[M,Npitch] = A[M,K] @ Wt[Npitch,K]^T -----

__global__ __launch_bounds__(256) void gemm_bf16(const __hip_bfloat16* __restrict__ A,
                                                 const __hip_bfloat16* __restrict__ Wt,
                                                 __hip_bfloat16* __restrict__ C,
                                                 int M, int K, int Npitch) {
    __shared__ __align__(16) __hip_bfloat16 sA[128 * 64];  // [row][k], 128B rows
    __shared__ __align__(16) __hip_bfloat16 sB[64 * 64];   // [n][k],   128B rows
    const int t = threadIdx.x;
    const int lane = t & 63;
    const int w = t >> 6;
    const int wy = w >> 1, wx = w & 1;
    const int quad = lane >> 4;
    const int l16 = lane & 15;
    const int row0 = blockIdx.y * 128;
    const int col0 = blockIdx.x * 64;

    floatx4 acc[4][2];
#pragma unroll
    for (int mt = 0; mt < 4; mt++)
#pragma unroll
        for (int nt = 0; nt < 2; nt++) acc[mt][nt] = 0;

    const int arow = t >> 3;
    const int koff = (t & 7) * 8;

    for (int k0 = 0; k0 < K; k0 += 64) {
#pragma unroll
        for (int r = 0; r < 4; r++) {
            int gm = row0 + r * 32 + arow;
            int gmc = (gm < M) ? gm : 0;
            async_copy16(A + (size_t)gmc * K + k0 + koff,
                         (char*)sA + r * 4096 + t * 16);
        }
#pragma unroll
        for (int r = 0; r < 2; r++) {
            int n = r * 32 + arow;
            async_copy16(Wt + (size_t)(col0 + n) * K + k0 + koff,
                         (char*)sB + r * 4096 + t * 16);
        }
        __syncthreads();

        short8 af[4][2], bfr[2][2];
#pragma unroll
        for (int mt = 0; mt < 4; mt++)
#pragma unroll
            for (int kk = 0; kk < 2; kk++)
                af[mt][kk] = *(const short8*)((const char*)sA +
                             (wy * 64 + mt * 16 + l16) * 128 + kk * 64 + quad * 16);
#pragma unroll
        for (int nt = 0; nt < 2; nt++)
#pragma unroll
            for (int kk = 0; kk < 2; kk++)
                bfr[nt][kk] = *(const short8*)((const char*)sB +
                              (wx * 32 + nt * 16 + l16) * 128 + kk * 64 + quad * 16);
#pragma unroll
        for (int kk = 0; kk < 2; kk++)
#pragma unroll
            for (int mt = 0; mt < 4; mt++)
#pragma unroll
                for (int nt = 0; nt < 2; nt++)
                    acc[mt][nt] = __builtin_amdgcn_mfma_f32_16x16x32_bf16(
                        af[mt][kk], bfr[nt][kk], acc[mt][nt], 0, 0, 0);
        __syncthreads();
    }

#pragma unroll
    for (int mt = 0; mt < 4; mt++) {
#pragma unroll
        for (int nt = 0; nt < 2; nt++) {
            int gn = col0 + wx * 32 + nt * 16 + l16;
            int gmb = row0 + wy * 64 + mt * 16 + quad * 4;
#pragma unroll
            for (int r = 0; r < 4; r++) {
                int gm = gmb + r;
                if (gm < M)
                    C[(size_t)gm * Npitch + gn] = __float2bfloat16(acc[mt][nt][r]);
            }
        }
    }
}

// ---------------- SpMM (CSR by dst) + bias + relu, bf16 gathers -------------
// v3: one wave per dst node; lanes split into 64/G groups of G lanes; each
// group owns one edge at a time and gathers its support row as G x 16B
// (ushort8) loads; U rounds unrolled => (64/G)*U edges in flight per wave.
// Edge index is CLAMPED to the row's last edge (tail gathers hit the same
// already-cached row -> no junk fetch; tail weight forced to 0).
// After the row, a shfl_xor butterfly over offsets {G..32} merges the group
// partials. FINAL=true fuses log_softmax over the 40 real classes
// (support pitch 64; pad cols are exactly zero) and writes fp32 [n,40].

template <int D, int G, int U, bool FINAL, typename OT>
__global__ __launch_bounds__(256) void spmm_bias_relu(const int* __restrict__ row_ptr,
                                                      const unsigned int* __restrict__ edge_pk,
                                                      const __hip_bfloat16* __restrict__ support,
                                                      const float* __restrict__ bias,
                                                      OT* __restrict__ out,
                                                      int n_nodes) {
    constexpr int NG = 64 / G;           // edge groups per wave
    constexpr int CH = NG * U;           // edges consumed per iteration
    int node = blockIdx.x * (256 / WAVE) + (threadIdx.x >> 6);
    if (node >= n_nodes) return;
    node = __builtin_amdgcn_readfirstlane(node);
    const int lane = threadIdx.x & 63;
    const int g = lane / G;              // edge-group id
    const int t = lane & (G - 1);        // lane-in-group: owns cols [t*8, t*8+8)
    int e = row_ptr[node];
    const int end = row_ptr[node + 1];
    const unsigned short* sup = (const unsigned short*)support + t * 8;

    float acc[8];
#pragma unroll
    for (int i = 0; i < 8; i++) acc[i] = 0.f;

    while (e < end) {
        const int base = e + g * U;      // this group's contiguous edge chunk
        unsigned int pk[U];
#pragma unroll
        for (int u = 0; u < U; u++) {
            int idx = base + u;
            if (idx > end - 1) idx = end - 1;   // clamp INSIDE row: re-gather of
            pk[u] = edge_pk[idx];               // cached row, no junk fetch
        }
        ushort8 v[U];
#pragma unroll
        for (int u = 0; u < U; u++)
            v[u] = *(const ushort8*)(sup + (size_t)(pk[u] >> 15) * D);
#pragma unroll
        for (int u = 0; u < U; u++) {
            float wq = (float)(pk[u] & 0x7fffu) * (1.f / 32767.f);
            float wt = (base + u < end) ? wq : 0.f;   // tail contributes 0
#pragma unroll
            for (int i = 0; i < 8; i++) acc[i] += bf2f(v[u][i]) * wt;
        }
        e += CH;
    }

    // merge group partials: butterfly over group-id bits (all lanes end with
    // the full sum for their column slice)
#pragma unroll
    for (int off = G; off < 64; off <<= 1)
#pragma unroll
        for (int i = 0; i < 8; i++) acc[i] += __shfl_xor(acc[i], off);

    if (!FINAL) {
        ushort8 o;
#pragma unroll
        for (int i = 0; i < 8; i++) {
            float r = acc[i] + bias[t * 8 + i];
            r = r > 0.f ? r : 0.f;
            __hip_bfloat16 b = __float2bfloat16(r);
            o[i] = *(unsigned short*)&b;
        }
        if (lane < G) {
            union { ushort8 s; uintx4 u; } cvt; cvt.s = o;
            __builtin_nontemporal_store(cvt.u,
                (uintx4*)((unsigned short*)out + (size_t)node * D + t * 8));
        }
    } else {
        // D==64 pitch, 40 real classes; fused log_softmax
        float r[8];
#pragma unroll
        for (int i = 0; i < 8; i++) {
            float x = acc[i] + bias[t * 8 + i];
            r[i] = x > 0.f ? x : 0.f;
        }
        float m = -INFINITY;
#pragma unroll
        for (int i = 0; i < 8; i++)
            if (t * 8 + i < 40) m = fmaxf(m, r[i]);
#pragma unroll
        for (int off = 1; off < G; off <<= 1) m = fmaxf(m, __shfl_xor(m, off));
        float s = 0.f;
#pragma unroll
        for (int i = 0; i < 8; i++)
            if (t * 8 + i < 40) s += __expf(r[i] - m);
#pragma unroll
        for (int off = 1; off < G; off <<= 1) s += __shfl_xor(s, off);
        const float lse = __logf(s);
        if (lane < 5) {                 // lanes 0..4 cover cols 0..39
            float* op = (float*)out + (size_t)node * 40 + lane * 8;
#pragma unroll
            for (int i = 0; i < 8; i++) op[i] = r[i] - m - lse;
        }
    }
}

// ---------------- launch ----------------------------------------------------

extern "C" void kernel_launch(void* const* d_in, const int* in_sizes, int n_in,
                              void* d_out, int out_size, void* d_ws, size_t ws_size,
                              hipStream_t stream) {
    const float* x    = (const float*)d_in[0];
    const int*   esrc = (const int*)d_in[1];
    const int*   edst = (const int*)d_in[2];
    const float* ew   = (const float*)d_in[3];
    const float* Wm[4] = {(const float*)d_in[4], (const float*)d_in[6],
                          (const float*)d_in[8], (const float*)d_in[10]};
    const float* bm[4] = {(const float*)d_in[5], (const float*)d_in[7],
                          (const float*)d_in[9], (const float*)d_in[11]};
    const int NFEAT = 512;
    const int n_nodes = in_sizes[0] / NFEAT;
    const int n_edges = in_sizes[1];
    float* out = (float*)d_out;

    // --- workspace carve ---
    char* wsp = (char*)d_ws;
    size_t off = 0;
    auto alloc = [&](size_t bytes) -> void* {
        void* p = wsp + off;
        off += (bytes + 255) & ~(size_t)255;
        return p;
    };
    __hip_bfloat16* Xb = (__hip_bfloat16*)alloc((size_t)n_nodes * 512 * sizeof(__hip_bfloat16));
    __hip_bfloat16* Sb = (__hip_bfloat16*)alloc((size_t)n_nodes * 256 * sizeof(__hip_bfloat16));
    __hip_bfloat16* Hb = (__hip_bfloat16*)alloc((size_t)n_nodes * 256 * sizeof(__hip_bfloat16));
    __hip_bfloat16* Wt1 = (__hip_bfloat16*)alloc(256 * 512 * sizeof(__hip_bfloat16));
    __hip_bfloat16* Wt2 = (__hip_bfloat16*)alloc(128 * 256 * sizeof(__hip_bfloat16));
    __hip_bfloat16* Wt3 = (__hip_bfloat16*)alloc(64 * 128 * sizeof(__hip_bfloat16));
    __hip_bfloat16* Wt4 = (__hip_bfloat16*)alloc(64 * 64 * sizeof(__hip_bfloat16));
    float* b4p     = (float*)alloc(64 * sizeof(float));
    int*   counts  = (int*)alloc((size_t)n_nodes * sizeof(int));
    int*   row_ptr = (int*)alloc(((size_t)n_nodes + 1) * sizeof(int));
    int*   row_cur = (int*)alloc((size_t)n_nodes * sizeof(int));
    int*   bsum    = (int*)alloc(1024 * sizeof(int));
    int*   boff    = (int*)alloc(1024 * sizeof(int));
    int*   gcur    = (int*)alloc(NBK * sizeof(int));
    unsigned int* edge_pk = (unsigned int*)alloc((size_t)n_edges * sizeof(unsigned int));
    // E2 staging (8B/edge) aliases Hb: Hb is first written by L1 SpMM, which
    // runs after phaseB completes (same stream) -> safe.
    uint2* E2 = (uint2*)Hb;
    (void)ws_size;

    // --- conversions ---
    long n4 = (long)n_nodes * 512 / 4;
    convert_x_kernel<<<(int)((n4 + 255) / 256), 256, 0, stream>>>(x, Xb, n4);
    prep_weights_kernel<<<(131072 + 32768 + 8192 + 4096 + 64 + 255) / 256, 256, 0, stream>>>(
        Wm[0], Wm[1], Wm[2], Wm[3], bm[3], Wt1, Wt2, Wt3, Wt4, b4p);

    // --- CSR build ---
    hipMemsetAsync(counts, 0, (size_t)n_nodes * sizeof(int), stream);
    hist_kernel<<<(n_edges + 255) / 256, 256, 0, stream>>>(edst, n_edges, counts);
    int nb = (n_nodes + 1023) / 1024;
    scan1_kernel<<<nb, 1024, 0, stream>>>(counts, n_nodes, row_ptr, bsum);
    scan2_kernel<<<1, 1024, 0, stream>>>(bsum, nb, boff);
    scan3_kernel<<<(n_nodes + 255) / 256, 256, 0, stream>>>(row_ptr, boff, n_nodes,
                                                            n_edges, row_cur, gcur);
    scatter_phaseA<<<(n_edges + CHA - 1) / CHA, 256, 0, stream>>>(esrc, edst, ew,
                                                                  n_edges, gcur, E2);
    scatter_phaseB<<<(n_edges + 255) / 256, 256, 0, stream>>>(E2, n_edges,
                                                              row_cur, edge_pk);

    // --- layers ---
    auto gemm = [&](const __hip_bfloat16* A, const __hip_bfloat16* Wt,
                    __hip_bfloat16* C, int K, int Npitch) {
        dim3 grid(Npitch / 64, (n_nodes + 127) / 128);
        gemm_bf16<<<grid, 256, 0, stream>>>(A, Wt, C, n_nodes, K, Npitch);
    };
    int spmm_blocks = (n_nodes + 3) / 4;

    // L1: 512 -> 256
    gemm(Xb, Wt1, Sb, 512, 256);
    spmm_bias_relu<256, 32, 4, false, __hip_bfloat16><<<spmm_blocks, 256, 0, stream>>>(
        row_ptr, edge_pk, Sb, bm[0], Hb, n_nodes);
    // L2: 256 -> 128
    gemm(Hb, Wt2, Sb, 256, 128);
    spmm_bias_relu<128, 16, 4, false, __hip_bfloat16><<<spmm_blocks, 256, 0, stream>>>(
        row_ptr, edge_pk, Sb, bm[1], Hb, n_nodes);
    // L3: 128 -> 64
    gemm(Hb, Wt3, Sb, 128, 64);
    spmm_bias_relu<64, 8, 2, false, __hip_bfloat16><<<spmm_blocks, 256, 0, stream>>>(
        row_ptr, edge_pk, Sb, bm[2], Hb, n_nodes);
    // L4: 64 -> 40 (N padded to 64; padded support cols/bias are zero)
    // fused log_softmax -> writes final fp32 [n,40] directly
    gemm(Hb, Wt4, Sb, 64, 64);
    spmm_bias_relu<64, 8, 2, true, float><<<spmm_blocks, 256, 0, stream>>>(
        row_ptr, edge_pk, Sb, b4p, out, n_nodes);
}

// Round 3
// 1023.575 us; speedup vs baseline: 1.1799x; 1.1073x over previous
//
#include <hip/hip_runtime.h>
#include <hip/hip_bf16.h>
#include <math.h>
#include <stdint.h>

// ---------------------------------------------------------------------------
// GCN 4-layer, bf16 datapath:
//   h = relu( A_w @ (h @ W) + b ) x4, then log_softmax (fp32 out).
//   - dst-CSR built once per call; edges packed u32 (src<<15 | w*32767)
//   - CSR scatter is 2-phase bucket-binned (dst>>8) so the final scatter
//     writes land in ~32KB windows (line-coalesced) instead of random 4B/64B
//   - GEMM: bf16 MFMA 16x16x32, tile 128x64, BK=64, global_load_lds staging
//   - SpMM is FETCH-bound at ~3.55 TB/s (L2-miss path plateau, measured over
//     3 rounds: time == FETCH_SIZE / 3.55 TB/s regardless of load width or
//     rows-in-flight). So L1 (the biggest layer) stores its support in fp8
//     e4m3 (HW cvt both ways): halves delivered bytes AND halves the 51MB
//     working set -> L2 hit rate rises -> FETCH drops >2x.
//   - SpMM v3 (bf16 layers): lane-GROUP per edge (G = D/8 lanes, 16B ushort8
//     gathers), edge index CLAMPED inside the row (tail re-reads the row's
//     last edge, L1-resident -> no junk fetch; weight forced to 0).
//     L4 variant fuses log_softmax (writes final fp32 [n,40] directly).
// ---------------------------------------------------------------------------

#define WAVE 64
#define NBK 512          // scatter buckets (dst >> 8)
#define CHA 8192         // edges per phaseA block
typedef __attribute__((ext_vector_type(8))) short short8;
typedef __attribute__((ext_vector_type(8))) unsigned short ushort8;
typedef __attribute__((ext_vector_type(4))) unsigned int uintx4;
typedef __attribute__((ext_vector_type(4))) float floatx4;
typedef __attribute__((ext_vector_type(2))) float floatx2;

__device__ __forceinline__ void async_copy16(const void* g, void* l) {
    __builtin_amdgcn_global_load_lds(
        (const __attribute__((address_space(1))) void*)g,
        (__attribute__((address_space(3))) void*)l, 16, 0, 0);
}
__device__ __forceinline__ float bf2f(unsigned short u) {
    union { unsigned int i; float f; } x; x.i = ((unsigned int)u) << 16; return x.f;
}

// ---------------- setup conversions ----------------

__global__ __launch_bounds__(256) void convert_x_kernel(const float* __restrict__ in,
                                                        __hip_bfloat16* __restrict__ out,
                                                        long n4) {
    long i = ((long)blockIdx.x * 256 + threadIdx.x);
    if (i >= n4) return;
    const float4 v = *(const float4*)(in + i * 4);
    __hip_bfloat16* o = out + i * 4;
    o[0] = __float2bfloat16(v.x); o[1] = __float2bfloat16(v.y);
    o[2] = __float2bfloat16(v.z); o[3] = __float2bfloat16(v.w);
}

// All weight transposes + bias pad in ONE kernel (launch-gap trim).
// Segments: Wt1 131072 | Wt2 32768 | Wt3 8192 | Wt4 4096 | b4p 64
__global__ __launch_bounds__(256) void prep_weights_kernel(
        const float* __restrict__ W1, const float* __restrict__ W2,
        const float* __restrict__ W3, const float* __restrict__ W4,
        const float* __restrict__ b4,
        __hip_bfloat16* __restrict__ Wt1, __hip_bfloat16* __restrict__ Wt2,
        __hip_bfloat16* __restrict__ Wt3, __hip_bfloat16* __restrict__ Wt4,
        float* __restrict__ b4p) {
    int idx = blockIdx.x * 256 + threadIdx.x;
    if (idx < 131072) {                       // Wt1: K=512 N=256
        int n = idx >> 9, k = idx & 511;
        Wt1[idx] = __float2bfloat16(W1[(size_t)k * 256 + n]);
    } else if (idx < 131072 + 32768) {        // Wt2: K=256 N=128
        int l = idx - 131072;
        int n = l >> 8, k = l & 255;
        Wt2[l] = __float2bfloat16(W2[(size_t)k * 128 + n]);
    } else if (idx < 131072 + 32768 + 8192) { // Wt3: K=128 N=64
        int l = idx - 131072 - 32768;
        int n = l >> 7, k = l & 127;
        Wt3[l] = __float2bfloat16(W3[(size_t)k * 64 + n]);
    } else if (idx < 131072 + 32768 + 8192 + 4096) { // Wt4: K=64 N=40 pad 64
        int l = idx - 131072 - 32768 - 8192;
        int n = l >> 6, k = l & 63;
        float v = (n < 40) ? W4[(size_t)k * 40 + n] : 0.f;
        Wt4[l] = __float2bfloat16(v);
    } else if (idx < 131072 + 32768 + 8192 + 4096 + 64) {
        int l = idx - 131072 - 32768 - 8192 - 4096;
        b4p[l] = (l < 40) ? b4[l] : 0.f;
    }
}

// ---------------- CSR build ----------------

__global__ __launch_bounds__(256) void hist_kernel(const int* __restrict__ dst,
                                                   int nE, int* __restrict__ counts) {
    int i = blockIdx.x * 256 + threadIdx.x;
    if (i < nE) atomicAdd(&counts[dst[i]], 1);
}

__global__ __launch_bounds__(1024) void scan1_kernel(const int* __restrict__ counts,
                                                     int n, int* __restrict__ partial,
                                                     int* __restrict__ bsum) {
    __shared__ int sm[1024];
    int tid = threadIdx.x;
    int i = blockIdx.x * 1024 + tid;
    int x = (i < n) ? counts[i] : 0;
    sm[tid] = x;
    __syncthreads();
    for (int off = 1; off < 1024; off <<= 1) {
        int add = 0;
        if (tid >= off) add = sm[tid - off];
        __syncthreads();
        if (tid >= off) sm[tid] += add;
        __syncthreads();
    }
    int incl = sm[tid];
    if (i < n) partial[i] = incl - x;
    if (tid == 1023) bsum[blockIdx.x] = incl;
}

__global__ __launch_bounds__(1024) void scan2_kernel(const int* __restrict__ bsum,
                                                     int nb, int* __restrict__ boff) {
    __shared__ int sm[1024];
    int tid = threadIdx.x;
    int x = (tid < nb) ? bsum[tid] : 0;
    sm[tid] = x;
    __syncthreads();
    for (int off = 1; off < 1024; off <<= 1) {
        int add = 0;
        if (tid >= off) add = sm[tid - off];
        __syncthreads();
        if (tid >= off) sm[tid] += add;
        __syncthreads();
    }
    if (tid < nb) boff[tid] = sm[tid] - x;
}

// finalize row_ptr; init row_cur and per-bucket cursors gcur[b]=row_ptr[b<<8]
__global__ __launch_bounds__(256) void scan3_kernel(int* __restrict__ row_ptr,
                                                    const int* __restrict__ boff,
                                                    int n, int nE,
                                                    int* __restrict__ row_cur,
                                                    int* __restrict__ gcur) {
    int i = blockIdx.x * 256 + threadIdx.x;
    if (i < n) {
        int v = row_ptr[i] + boff[i >> 10];
        row_ptr[i] = v;
        row_cur[i] = v;
        if ((i & 255) == 0) gcur[i >> 8] = v;
    }
    if (i == 0) row_ptr[n] = nE;
}

// Phase A: bucket edges by dst>>8 into E2 staging (u64: .y=dst, .x=src<<15|w15).
// Per-block LDS histogram + one global reservation per (block,bucket); writes
// land as ~16-entry runs per bucket region (line-friendly).
__global__ __launch_bounds__(256) void scatter_phaseA(const int* __restrict__ src,
                                                      const int* __restrict__ dst,
                                                      const float* __restrict__ ew,
                                                      int nE,
                                                      int* __restrict__ gcur,
                                                      uint2* __restrict__ E2) {
    __shared__ int hist[NBK];
    __shared__ int cur[NBK];
    const int t = threadIdx.x;
    const long e0 = (long)blockIdx.x * CHA;
    const int cnt = (int)((nE - e0 < CHA) ? (nE - e0) : CHA);

    for (int i = t; i < NBK; i += 256) hist[i] = 0;
    __syncthreads();
    for (int i = t; i < cnt; i += 256)
        atomicAdd(&hist[dst[e0 + i] >> 8], 1);
    __syncthreads();
    for (int i = t; i < NBK; i += 256) {
        int h = hist[i];
        cur[i] = h ? atomicAdd(&gcur[i], h) : 0;   // global base for this block
    }
    __syncthreads();
    for (int i = t; i < cnt; i += 256) {
        int d = dst[e0 + i];
        unsigned int w15 = (unsigned int)(ew[e0 + i] * 32767.f + 0.5f);
        if (w15 > 32767u) w15 = 32767u;
        int pos = atomicAdd(&cur[d >> 8], 1);      // LDS atomic -> global slot
        E2[pos] = make_uint2(((unsigned int)src[e0 + i] << 15) | w15,
                             (unsigned int)d);
    }
}

// Phase B: exact CSR placement. Each bucket's writes span only ~32KB of
// edge_pk, so the 4B scatters coalesce in L2 instead of costing a line each.
__global__ __launch_bounds__(256) void scatter_phaseB(const uint2* __restrict__ E2,
                                                      int nE,
                                                      int* __restrict__ row_cur,
                                                      unsigned int* __restrict__ edge_pk) {
    int i = blockIdx.x * 256 + threadIdx.x;
    if (i < nE) {
        uint2 e = E2[i];
        int pos = atomicAdd(&row_cur[e.y], 1);
        edge_pk[pos] = e.x;
    }
}

// ---------------- bf16 MFMA GEMM: C[M,Npitch] = A[M,K] @ Wt[Npitch,K]^T -----
// OUTM: 0 = bf16 output, 1 = fp8 e4m3 output (HW cvt_pk_fp8_f32, RNE+sat)

template <int OUTM>
__global__ __launch_bounds__(256) void gemm_bf16(const __hip_bfloat16* __restrict__ A,
                                                 const __hip_bfloat16* __restrict__ Wt,
                                                 void* __restrict__ C,
                                                 int M, int K, int Npitch) {
    __shared__ __align__(16) __hip_bfloat16 sA[128 * 64];  // [row][k], 128B rows
    __shared__ __align__(16) __hip_bfloat16 sB[64 * 64];   // [n][k],   128B rows
    const int t = threadIdx.x;
    const int lane = t & 63;
    const int w = t >> 6;
    const int wy = w >> 1, wx = w & 1;
    const int quad = lane >> 4;
    const int l16 = lane & 15;
    const int row0 = blockIdx.y * 128;
    const int col0 = blockIdx.x * 64;

    floatx4 acc[4][2];
#pragma unroll
    for (int mt = 0; mt < 4; mt++)
#pragma unroll
        for (int nt = 0; nt < 2; nt++) acc[mt][nt] = 0;

    const int arow = t >> 3;
    const int koff = (t & 7) * 8;

    for (int k0 = 0; k0 < K; k0 += 64) {
#pragma unroll
        for (int r = 0; r < 4; r++) {
            int gm = row0 + r * 32 + arow;
            int gmc = (gm < M) ? gm : 0;
            async_copy16(A + (size_t)gmc * K + k0 + koff,
                         (char*)sA + r * 4096 + t * 16);
        }
#pragma unroll
        for (int r = 0; r < 2; r++) {
            int n = r * 32 + arow;
            async_copy16(Wt + (size_t)(col0 + n) * K + k0 + koff,
                         (char*)sB + r * 4096 + t * 16);
        }
        __syncthreads();

        short8 af[4][2], bfr[2][2];
#pragma unroll
        for (int mt = 0; mt < 4; mt++)
#pragma unroll
            for (int kk = 0; kk < 2; kk++)
                af[mt][kk] = *(const short8*)((const char*)sA +
                             (wy * 64 + mt * 16 + l16) * 128 + kk * 64 + quad * 16);
#pragma unroll
        for (int nt = 0; nt < 2; nt++)
#pragma unroll
            for (int kk = 0; kk < 2; kk++)
                bfr[nt][kk] = *(const short8*)((const char*)sB +
                              (wx * 32 + nt * 16 + l16) * 128 + kk * 64 + quad * 16);
#pragma unroll
        for (int kk = 0; kk < 2; kk++)
#pragma unroll
            for (int mt = 0; mt < 4; mt++)
#pragma unroll
                for (int nt = 0; nt < 2; nt++)
                    acc[mt][nt] = __builtin_amdgcn_mfma_f32_16x16x32_bf16(
                        af[mt][kk], bfr[nt][kk], acc[mt][nt], 0, 0, 0);
        __syncthreads();
    }

#pragma unroll
    for (int mt = 0; mt < 4; mt++) {
#pragma unroll
        for (int nt = 0; nt < 2; nt++) {
            int gn = col0 + wx * 32 + nt * 16 + l16;
            int gmb = row0 + wy * 64 + mt * 16 + quad * 4;
#pragma unroll
            for (int r = 0; r < 4; r++) {
                int gm = gmb + r;
                if (gm < M) {
                    if (OUTM == 0) {
                        ((__hip_bfloat16*)C)[(size_t)gm * Npitch + gn] =
                            __float2bfloat16(acc[mt][nt][r]);
                    } else {
                        float v = acc[mt][nt][r];
                        int p = __builtin_amdgcn_cvt_pk_fp8_f32(v, v, 0, false);
                        ((unsigned char*)C)[(size_t)gm * Npitch + gn] =
                            (unsigned char)(p & 0xff);
                    }
                }
            }
        }
    }
}

// ---------------- SpMM L1: fp8 support (D=256), bias+relu, bf16 out --------
// G=16 lanes/edge-group x 16B uintx4 gathers (16 fp8 each); 4 groups x U=4
// = 16 edges in flight/wave. HW v_cvt_pk_f32_fp8 decode (2 floats/instr).
// Edge index clamped inside the row (cached re-read, no junk fetch).

__global__ __launch_bounds__(256) void spmm_fp8_256(const int* __restrict__ row_ptr,
                                                    const unsigned int* __restrict__ edge_pk,
                                                    const unsigned char* __restrict__ sup8,
                                                    const float* __restrict__ bias,
                                                    __hip_bfloat16* __restrict__ out,
                                                    int n_nodes) {
    constexpr int G = 16, U = 4, CH = (64 / G) * U;   // 16 edges/iter
    int node = blockIdx.x * (256 / WAVE) + (threadIdx.x >> 6);
    if (node >= n_nodes) return;
    node = __builtin_amdgcn_readfirstlane(node);
    const int lane = threadIdx.x & 63;
    const int g = lane >> 4;             // edge-group id (0..3)
    const int t = lane & 15;             // owns cols [t*16, t*16+16)
    int e = row_ptr[node];
    const int end = row_ptr[node + 1];
    const unsigned char* sup = sup8 + t * 16;

    float acc[16];
#pragma unroll
    for (int i = 0; i < 16; i++) acc[i] = 0.f;

    while (e < end) {
        const int base = e + g * U;
        unsigned int pk[U];
#pragma unroll
        for (int u = 0; u < U; u++) {
            int idx = base + u;
            if (idx > end - 1) idx = end - 1;   // clamp INSIDE row
            pk[u] = edge_pk[idx];
        }
        uintx4 v[U];
#pragma unroll
        for (int u = 0; u < U; u++)
            v[u] = *(const uintx4*)(sup + (size_t)(pk[u] >> 15) * 256);
#pragma unroll
        for (int u = 0; u < U; u++) {
            float wq = (float)(pk[u] & 0x7fffu) * (1.f / 32767.f);
            float wt = (base + u < end) ? wq : 0.f;
#pragma unroll
            for (int d = 0; d < 4; d++) {
                floatx2 lo = __builtin_amdgcn_cvt_pk_f32_fp8(v[u][d], false);
                floatx2 hi = __builtin_amdgcn_cvt_pk_f32_fp8(v[u][d], true);
                acc[d * 4 + 0] += lo[0] * wt;
                acc[d * 4 + 1] += lo[1] * wt;
                acc[d * 4 + 2] += hi[0] * wt;
                acc[d * 4 + 3] += hi[1] * wt;
            }
        }
        e += CH;
    }

    // merge the 4 edge-groups: butterfly over lane bits 4,5
#pragma unroll
    for (int off = 16; off < 64; off <<= 1)
#pragma unroll
        for (int i = 0; i < 16; i++) acc[i] += __shfl_xor(acc[i], off);

    if (lane < 16) {
        ushort8 o0, o1;
#pragma unroll
        for (int i = 0; i < 8; i++) {
            float r0 = acc[i] + bias[t * 16 + i];
            float r1 = acc[8 + i] + bias[t * 16 + 8 + i];
            r0 = r0 > 0.f ? r0 : 0.f;
            r1 = r1 > 0.f ? r1 : 0.f;
            __hip_bfloat16 b0 = __float2bfloat16(r0);
            __hip_bfloat16 b1 = __float2bfloat16(r1);
            o0[i] = *(unsigned short*)&b0;
            o1[i] = *(unsigned short*)&b1;
        }
        union { ushort8 s; uintx4 u; } c0, c1; c0.s = o0; c1.s = o1;
        unsigned short* op = (unsigned short*)out + (size_t)node * 256 + t * 16;
        __builtin_nontemporal_store(c0.u, (uintx4*)op);
        __builtin_nontemporal_store(c1.u, (uintx4*)(op + 8));
    }
}

// ---------------- SpMM (CSR by dst) + bias + relu, bf16 gathers -------------
// v3: one wave per dst node; lanes split into 64/G groups of G lanes; each
// group owns one edge at a time and gathers its support row as G x 16B
// (ushort8) loads; U rounds unrolled => (64/G)*U edges in flight per wave.
// Edge index is CLAMPED to the row's last edge (tail gathers hit the same
// already-cached row -> no junk fetch; tail weight forced to 0).
// After the row, a shfl_xor butterfly over offsets {G..32} merges the group
// partials. FINAL=true fuses log_softmax over the 40 real classes
// (support pitch 64; pad cols are exactly zero) and writes fp32 [n,40].

template <int D, int G, int U, bool FINAL, typename OT>
__global__ __launch_bounds__(256) void spmm_bias_relu(const int* __restrict__ row_ptr,
                                                      const unsigned int* __restrict__ edge_pk,
                                                      const __hip_bfloat16* __restrict__ support,
                                                      const float* __restrict__ bias,
                                                      OT* __restrict__ out,
                                                      int n_nodes) {
    constexpr int NG = 64 / G;           // edge groups per wave
    constexpr int CH = NG * U;           // edges consumed per iteration
    int node = blockIdx.x * (256 / WAVE) + (threadIdx.x >> 6);
    if (node >= n_nodes) return;
    node = __builtin_amdgcn_readfirstlane(node);
    const int lane = threadIdx.x & 63;
    const int g = lane / G;              // edge-group id
    const int t = lane & (G - 1);        // lane-in-group: owns cols [t*8, t*8+8)
    int e = row_ptr[node];
    const int end = row_ptr[node + 1];
    const unsigned short* sup = (const unsigned short*)support + t * 8;

    float acc[8];
#pragma unroll
    for (int i = 0; i < 8; i++) acc[i] = 0.f;

    while (e < end) {
        const int base = e + g * U;      // this group's contiguous edge chunk
        unsigned int pk[U];
#pragma unroll
        for (int u = 0; u < U; u++) {
            int idx = base + u;
            if (idx > end - 1) idx = end - 1;   // clamp INSIDE row: re-gather of
            pk[u] = edge_pk[idx];               // cached row, no junk fetch
        }
        ushort8 v[U];
#pragma unroll
        for (int u = 0; u < U; u++)
            v[u] = *(const ushort8*)(sup + (size_t)(pk[u] >> 15) * D);
#pragma unroll
        for (int u = 0; u < U; u++) {
            float wq = (float)(pk[u] & 0x7fffu) * (1.f / 32767.f);
            float wt = (base + u < end) ? wq : 0.f;   // tail contributes 0
#pragma unroll
            for (int i = 0; i < 8; i++) acc[i] += bf2f(v[u][i]) * wt;
        }
        e += CH;
    }

    // merge group partials: butterfly over group-id bits (all lanes end with
    // the full sum for their column slice)
#pragma unroll
    for (int off = G; off < 64; off <<= 1)
#pragma unroll
        for (int i = 0; i < 8; i++) acc[i] += __shfl_xor(acc[i], off);

    if (!FINAL) {
        ushort8 o;
#pragma unroll
        for (int i = 0; i < 8; i++) {
            float r = acc[i] + bias[t * 8 + i];
            r = r > 0.f ? r : 0.f;
            __hip_bfloat16 b = __float2bfloat16(r);
            o[i] = *(unsigned short*)&b;
        }
        if (lane < G) {
            union { ushort8 s; uintx4 u; } cvt; cvt.s = o;
            __builtin_nontemporal_store(cvt.u,
                (uintx4*)((unsigned short*)out + (size_t)node * D + t * 8));
        }
    } else {
        // D==64 pitch, 40 real classes; fused log_softmax
        float r[8];
#pragma unroll
        for (int i = 0; i < 8; i++) {
            float x = acc[i] + bias[t * 8 + i];
            r[i] = x > 0.f ? x : 0.f;
        }
        float m = -INFINITY;
#pragma unroll
        for (int i = 0; i < 8; i++)
            if (t * 8 + i < 40) m = fmaxf(m, r[i]);
#pragma unroll
        for (int off = 1; off < G; off <<= 1) m = fmaxf(m, __shfl_xor(m, off));
        float s = 0.f;
#pragma unroll
        for (int i = 0; i < 8; i++)
            if (t * 8 + i < 40) s += __expf(r[i] - m);
#pragma unroll
        for (int off = 1; off < G; off <<= 1) s += __shfl_xor(s, off);
        const float lse = __logf(s);
        if (lane < 5) {                 // lanes 0..4 cover cols 0..39
            float* op = (float*)out + (size_t)node * 40 + lane * 8;
#pragma unroll
            for (int i = 0; i < 8; i++) op[i] = r[i] - m - lse;
        }
    }
}

// ---------------- launch ----------------------------------------------------

extern "C" void kernel_launch(void* const* d_in, const int* in_sizes, int n_in,
                              void* d_out, int out_size, void* d_ws, size_t ws_size,
                              hipStream_t stream) {
    const float* x    = (const float*)d_in[0];
    const int*   esrc = (const int*)d_in[1];
    const int*   edst = (const int*)d_in[2];
    const float* ew   = (const float*)d_in[3];
    const float* Wm[4] = {(const float*)d_in[4], (const float*)d_in[6],
                          (const float*)d_in[8], (const float*)d_in[10]};
    const float* bm[4] = {(const float*)d_in[5], (const float*)d_in[7],
                          (const float*)d_in[9], (const float*)d_in[11]};
    const int NFEAT = 512;
    const int n_nodes = in_sizes[0] / NFEAT;
    const int n_edges = in_sizes[1];
    float* out = (float*)d_out;

    // --- workspace carve ---
    char* wsp = (char*)d_ws;
    size_t off = 0;
    auto alloc = [&](size_t bytes) -> void* {
        void* p = wsp + off;
        off += (bytes + 255) & ~(size_t)255;
        return p;
    };
    __hip_bfloat16* Xb = (__hip_bfloat16*)alloc((size_t)n_nodes * 512 * sizeof(__hip_bfloat16));
    __hip_bfloat16* Sb = (__hip_bfloat16*)alloc((size_t)n_nodes * 256 * sizeof(__hip_bfloat16));
    __hip_bfloat16* Hb = (__hip_bfloat16*)alloc((size_t)n_nodes * 256 * sizeof(__hip_bfloat16));
    __hip_bfloat16* Wt1 = (__hip_bfloat16*)alloc(256 * 512 * sizeof(__hip_bfloat16));
    __hip_bfloat16* Wt2 = (__hip_bfloat16*)alloc(128 * 256 * sizeof(__hip_bfloat16));
    __hip_bfloat16* Wt3 = (__hip_bfloat16*)alloc(64 * 128 * sizeof(__hip_bfloat16));
    __hip_bfloat16* Wt4 = (__hip_bfloat16*)alloc(64 * 64 * sizeof(__hip_bfloat16));
    float* b4p     = (float*)alloc(64 * sizeof(float));
    int*   counts  = (int*)alloc((size_t)n_nodes * sizeof(int));
    int*   row_ptr = (int*)alloc(((size_t)n_nodes + 1) * sizeof(int));
    int*   row_cur = (int*)alloc((size_t)n_nodes * sizeof(int));
    int*   bsum    = (int*)alloc(1024 * sizeof(int));
    int*   boff    = (int*)alloc(1024 * sizeof(int));
    int*   gcur    = (int*)alloc(NBK * sizeof(int));
    unsigned int* edge_pk = (unsigned int*)alloc((size_t)n_edges * sizeof(unsigned int));
    // E2 staging (8B/edge) aliases Hb: Hb is first written by L1 SpMM, which
    // runs after phaseB completes (same stream) -> safe.
    uint2* E2 = (uint2*)Hb;
    // L1 fp8 support aliases Sb (GEMM1 writes fp8 into it, SpMM1 reads it,
    // then GEMM2 overwrites the same region as bf16 -> sequential, safe).
    unsigned char* Sb8 = (unsigned char*)Sb;
    (void)ws_size;

    // --- conversions ---
    long n4 = (long)n_nodes * 512 / 4;
    convert_x_kernel<<<(int)((n4 + 255) / 256), 256, 0, stream>>>(x, Xb, n4);
    prep_weights_kernel<<<(131072 + 32768 + 8192 + 4096 + 64 + 255) / 256, 256, 0, stream>>>(
        Wm[0], Wm[1], Wm[2], Wm[3], bm[3], Wt1, Wt2, Wt3, Wt4, b4p);

    // --- CSR build ---
    hipMemsetAsync(counts, 0, (size_t)n_nodes * sizeof(int), stream);
    hist_kernel<<<(n_edges + 255) / 256, 256, 0, stream>>>(edst, n_edges, counts);
    int nb = (n_nodes + 1023) / 1024;
    scan1_kernel<<<nb, 1024, 0, stream>>>(counts, n_nodes, row_ptr, bsum);
    scan2_kernel<<<1, 1024, 0, stream>>>(bsum, nb, boff);
    scan3_kernel<<<(n_nodes + 255) / 256, 256, 0, stream>>>(row_ptr, boff, n_nodes,
                                                            n_edges, row_cur, gcur);
    scatter_phaseA<<<(n_edges + CHA - 1) / CHA, 256, 0, stream>>>(esrc, edst, ew,
                                                                  n_edges, gcur, E2);
    scatter_phaseB<<<(n_edges + 255) / 256, 256, 0, stream>>>(E2, n_edges,
                                                              row_cur, edge_pk);

    // --- layers ---
    int spmm_blocks = (n_nodes + 3) / 4;
    dim3 g1(256 / 64, (n_nodes + 127) / 128);
    dim3 g2(128 / 64, (n_nodes + 127) / 128);
    dim3 g3(64 / 64, (n_nodes + 127) / 128);

    // L1: 512 -> 256 (support stored fp8 e4m3; gathers halve fetch bytes)
    gemm_bf16<1><<<g1, 256, 0, stream>>>(Xb, Wt1, Sb8, n_nodes, 512, 256);
    spmm_fp8_256<<<spmm_blocks, 256, 0, stream>>>(
        row_ptr, edge_pk, Sb8, bm[0], Hb, n_nodes);
    // L2: 256 -> 128
    gemm_bf16<0><<<g2, 256, 0, stream>>>(Hb, Wt2, Sb, n_nodes, 256, 128);
    spmm_bias_relu<128, 16, 4, false, __hip_bfloat16><<<spmm_blocks, 256, 0, stream>>>(
        row_ptr, edge_pk, Sb, bm[1], Hb, n_nodes);
    // L3: 128 -> 64
    gemm_bf16<0><<<g3, 256, 0, stream>>>(Hb, Wt3, Sb, n_nodes, 128, 64);
    spmm_bias_relu<64, 8, 2, false, __hip_bfloat16><<<spmm_blocks, 256, 0, stream>>>(
        row_ptr, edge_pk, Sb, bm[2], Hb, n_nodes);
    // L4: 64 -> 40 (N padded to 64; padded support cols/bias are zero)
    // fused log_softmax -> writes final fp32 [n,40] directly
    gemm_bf16<0><<<g3, 256, 0, stream>>>(Hb, Wt4, Sb, n_nodes, 64, 64);
    spmm_bias_relu<64, 8, 2, true, float><<<spmm_blocks, 256, 0, stream>>>(
        row_ptr, edge_pk, Sb, b4p, out, n_nodes);
}

// Round 4
// 863.870 us; speedup vs baseline: 1.3980x; 1.1849x over previous
//
#include <hip/hip_runtime.h>
#include <hip/hip_bf16.h>
#include <math.h>
#include <stdint.h>

// ---------------------------------------------------------------------------
// GCN 4-layer, bf16 datapath:
//   h = relu( A_w @ (h @ W) + b ) x4, then log_softmax (fp32 out).
//   - dst-CSR built once per call; edges packed u32 (src<<15 | w*32767)
//   - CSR build is fully bucket-local (bucket = dst>>8):
//       bucket_hist (LDS 512-bin) -> bucket_scan (bbase) -> phaseA (LDS-binned
//       scatter into bucket regions) -> phaseB2 (one block per bucket: LDS
//       per-node hist + scan -> row_ptr AND exact CSR placement, LDS atomics
//       only). Global atomics: ~200K total (vs 6.4M before); the old
//       hist/phaseB global-atomic kernels ran at HBM write-through rate
//       (~100 MB WRITE_SIZE each, 128 us + ~100 us).
//   - GEMM: bf16 MFMA 16x16x32, tile 128x64, BK=64, global_load_lds staging
//   - SpMM is FETCH-bound at ~3.55 TB/s (L2-miss path plateau): L1 stores its
//     support in fp8 e4m3 (HW cvt both ways) -> halves bytes + working set.
//   - SpMM v3 (bf16 layers): lane-GROUP per edge (G = D/8 lanes, 16B ushort8
//     gathers), edge index CLAMPED inside the row (tail re-reads the row's
//     last edge, L1-resident -> no junk fetch; weight forced to 0).
//     L4 variant fuses log_softmax (writes final fp32 [n,40] directly).
// ---------------------------------------------------------------------------

#define WAVE 64
#define NBK 512          // scatter buckets (dst >> 8); covers up to 131072 nodes
#define CHA 8192         // edges per histogram/phaseA block
typedef __attribute__((ext_vector_type(8))) short short8;
typedef __attribute__((ext_vector_type(8))) unsigned short ushort8;
typedef __attribute__((ext_vector_type(4))) unsigned int uintx4;
typedef __attribute__((ext_vector_type(4))) float floatx4;
typedef __attribute__((ext_vector_type(2))) float floatx2;

__device__ __forceinline__ void async_copy16(const void* g, void* l) {
    __builtin_amdgcn_global_load_lds(
        (const __attribute__((address_space(1))) void*)g,
        (__attribute__((address_space(3))) void*)l, 16, 0, 0);
}
__device__ __forceinline__ float bf2f(unsigned short u) {
    union { unsigned int i; float f; } x; x.i = ((unsigned int)u) << 16; return x.f;
}

// ---------------- setup conversions ----------------

__global__ __launch_bounds__(256) void convert_x_kernel(const float* __restrict__ in,
                                                        __hip_bfloat16* __restrict__ out,
                                                        long n4) {
    long i = ((long)blockIdx.x * 256 + threadIdx.x);
    if (i >= n4) return;
    const float4 v = *(const float4*)(in + i * 4);
    __hip_bfloat16* o = out + i * 4;
    o[0] = __float2bfloat16(v.x); o[1] = __float2bfloat16(v.y);
    o[2] = __float2bfloat16(v.z); o[3] = __float2bfloat16(v.w);
}

// All weight transposes + bias pad in ONE kernel (launch-gap trim).
// Segments: Wt1 131072 | Wt2 32768 | Wt3 8192 | Wt4 4096 | b4p 64
__global__ __launch_bounds__(256) void prep_weights_kernel(
        const float* __restrict__ W1, const float* __restrict__ W2,
        const float* __restrict__ W3, const float* __restrict__ W4,
        const float* __restrict__ b4,
        __hip_bfloat16* __restrict__ Wt1, __hip_bfloat16* __restrict__ Wt2,
        __hip_bfloat16* __restrict__ Wt3, __hip_bfloat16* __restrict__ Wt4,
        float* __restrict__ b4p) {
    int idx = blockIdx.x * 256 + threadIdx.x;
    if (idx < 131072) {                       // Wt1: K=512 N=256
        int n = idx >> 9, k = idx & 511;
        Wt1[idx] = __float2bfloat16(W1[(size_t)k * 256 + n]);
    } else if (idx < 131072 + 32768) {        // Wt2: K=256 N=128
        int l = idx - 131072;
        int n = l >> 8, k = l & 255;
        Wt2[l] = __float2bfloat16(W2[(size_t)k * 128 + n]);
    } else if (idx < 131072 + 32768 + 8192) { // Wt3: K=128 N=64
        int l = idx - 131072 - 32768;
        int n = l >> 7, k = l & 127;
        Wt3[l] = __float2bfloat16(W3[(size_t)k * 64 + n]);
    } else if (idx < 131072 + 32768 + 8192 + 4096) { // Wt4: K=64 N=40 pad 64
        int l = idx - 131072 - 32768 - 8192;
        int n = l >> 6, k = l & 63;
        float v = (n < 40) ? W4[(size_t)k * 40 + n] : 0.f;
        Wt4[l] = __float2bfloat16(v);
    } else if (idx < 131072 + 32768 + 8192 + 4096 + 64) {
        int l = idx - 131072 - 32768 - 8192 - 4096;
        b4p[l] = (l < 40) ? b4[l] : 0.f;
    }
}

// ---------------- CSR build (bucket-local, LDS atomics) ----------------

// Coarse 512-bin histogram of dst>>8. LDS-privatized; 512 global atomics/block.
__global__ __launch_bounds__(256) void bucket_hist(const int* __restrict__ dst,
                                                   int nE, int* __restrict__ bhist) {
    __shared__ int h[NBK];
    const int t = threadIdx.x;
    const long e0 = (long)blockIdx.x * CHA;
    const int cnt = (int)((nE - e0 < CHA) ? (nE - e0) : CHA);
    for (int i = t; i < NBK; i += 256) h[i] = 0;
    __syncthreads();
    for (int i = t; i < cnt; i += 256)
        atomicAdd(&h[dst[e0 + i] >> 8], 1);
    __syncthreads();
    for (int i = t; i < NBK; i += 256)
        if (h[i]) atomicAdd(&bhist[i], h[i]);
}

// Exclusive scan of the 512 bucket counts -> bbase[513]; seeds phaseA cursors.
__global__ __launch_bounds__(512) void bucket_scan(const int* __restrict__ bhist,
                                                   int* __restrict__ bbase,
                                                   int* __restrict__ gcur) {
    __shared__ int sm[NBK];
    const int t = threadIdx.x;
    int x = bhist[t];
    sm[t] = x;
    __syncthreads();
    for (int off = 1; off < NBK; off <<= 1) {
        int add = (t >= off) ? sm[t - off] : 0;
        __syncthreads();
        if (t >= off) sm[t] += add;
        __syncthreads();
    }
    int excl = sm[t] - x;
    bbase[t] = excl;
    gcur[t] = excl;
    if (t == NBK - 1) bbase[NBK] = sm[t];
}

// Phase A: bucket edges by dst>>8 into E2 staging (u64: .y=dst, .x=src<<15|w15).
// Per-block LDS histogram + one global reservation per (block,bucket); writes
// land as ~16-entry runs per bucket region (line-friendly).
__global__ __launch_bounds__(256) void scatter_phaseA(const int* __restrict__ src,
                                                      const int* __restrict__ dst,
                                                      const float* __restrict__ ew,
                                                      int nE,
                                                      int* __restrict__ gcur,
                                                      uint2* __restrict__ E2) {
    __shared__ int hist[NBK];
    __shared__ int cur[NBK];
    const int t = threadIdx.x;
    const long e0 = (long)blockIdx.x * CHA;
    const int cnt = (int)((nE - e0 < CHA) ? (nE - e0) : CHA);

    for (int i = t; i < NBK; i += 256) hist[i] = 0;
    __syncthreads();
    for (int i = t; i < cnt; i += 256)
        atomicAdd(&hist[dst[e0 + i] >> 8], 1);
    __syncthreads();
    for (int i = t; i < NBK; i += 256) {
        int h = hist[i];
        cur[i] = h ? atomicAdd(&gcur[i], h) : 0;   // global base for this block
    }
    __syncthreads();
    for (int i = t; i < cnt; i += 256) {
        int d = dst[e0 + i];
        unsigned int w15 = (unsigned int)(ew[e0 + i] * 32767.f + 0.5f);
        if (w15 > 32767u) w15 = 32767u;
        int pos = atomicAdd(&cur[d >> 8], 1);      // LDS atomic -> global slot
        E2[pos] = make_uint2(((unsigned int)src[e0 + i] << 15) | w15,
                             (unsigned int)d);
    }
}

// Phase B2: one block per bucket. LDS per-node (256-bin) histogram + scan of
// this bucket's E2 segment -> writes row_ptr for the bucket's nodes AND
// scatters edges to exact CSR slots with LDS-only cursors. Global traffic is
// the sequential E2 read + in-window edge_pk writes; zero global atomics.
__global__ __launch_bounds__(256) void scatter_phaseB2(const uint2* __restrict__ E2,
                                                       const int* __restrict__ bbase,
                                                       int n_nodes, int nE,
                                                       int* __restrict__ row_ptr,
                                                       unsigned int* __restrict__ edge_pk) {
    __shared__ int cnt[256];
    __shared__ int pfx[256];
    __shared__ int cur[256];
    const int b = blockIdx.x;
    const int t = threadIdx.x;
    const int s = bbase[b];
    const int e = bbase[b + 1];

    cnt[t] = 0;
    __syncthreads();
    for (int i = s + t; i < e; i += 256)
        atomicAdd(&cnt[E2[i].y & 255], 1);
    __syncthreads();
    pfx[t] = cnt[t];
    __syncthreads();
    for (int off = 1; off < 256; off <<= 1) {
        int add = (t >= off) ? pfx[t - off] : 0;
        __syncthreads();
        if (t >= off) pfx[t] += add;
        __syncthreads();
    }
    const int excl = pfx[t] - cnt[t];
    const int node = b * 256 + t;
    if (node < n_nodes) row_ptr[node] = s + excl;
    if (b == 0 && t == 0) row_ptr[n_nodes] = nE;
    cur[t] = s + excl;
    __syncthreads();
    for (int i = s + t; i < e; i += 256) {
        uint2 ed = E2[i];
        int p = atomicAdd(&cur[ed.y & 255], 1);    // LDS atomic
        edge_pk[p] = ed.x;
    }
}

// ---------------- bf16 MFMA GEMM: C[M,Npitch] = A[M,K] @ Wt[Npitch,K]^T -----
// OUTM: 0 = bf16 output, 1 = fp8 e4m3 output (HW cvt_pk_fp8_f32, RNE+sat)

template <int OUTM>
__global__ __launch_bounds__(256) void gemm_bf16(const __hip_bfloat16* __restrict__ A,
                                                 const __hip_bfloat16* __restrict__ Wt,
                                                 void* __restrict__ C,
                                                 int M, int K, int Npitch) {
    __shared__ __align__(16) __hip_bfloat16 sA[128 * 64];  // [row][k], 128B rows
    __shared__ __align__(16) __hip_bfloat16 sB[64 * 64];   // [n][k],   128B rows
    const int t = threadIdx.x;
    const int lane = t & 63;
    const int w = t >> 6;
    const int wy = w >> 1, wx = w & 1;
    const int quad = lane >> 4;
    const int l16 = lane & 15;
    const int row0 = blockIdx.y * 128;
    const int col0 = blockIdx.x * 64;

    floatx4 acc[4][2];
#pragma unroll
    for (int mt = 0; mt < 4; mt++)
#pragma unroll
        for (int nt = 0; nt < 2; nt++) acc[mt][nt] = 0;

    const int arow = t >> 3;
    const int koff = (t & 7) * 8;

    for (int k0 = 0; k0 < K; k0 += 64) {
#pragma unroll
        for (int r = 0; r < 4; r++) {
            int gm = row0 + r * 32 + arow;
            int gmc = (gm < M) ? gm : 0;
            async_copy16(A + (size_t)gmc * K + k0 + koff,
                         (char*)sA + r * 4096 + t * 16);
        }
#pragma unroll
        for (int r = 0; r < 2; r++) {
            int n = r * 32 + arow;
            async_copy16(Wt + (size_t)(col0 + n) * K + k0 + koff,
                         (char*)sB + r * 4096 + t * 16);
        }
        __syncthreads();

        short8 af[4][2], bfr[2][2];
#pragma unroll
        for (int mt = 0; mt < 4; mt++)
#pragma unroll
            for (int kk = 0; kk < 2; kk++)
                af[mt][kk] = *(const short8*)((const char*)sA +
                             (wy * 64 + mt * 16 + l16) * 128 + kk * 64 + quad * 16);
#pragma unroll
        for (int nt = 0; nt < 2; nt++)
#pragma unroll
            for (int kk = 0; kk < 2; kk++)
                bfr[nt][kk] = *(const short8*)((const char*)sB +
                              (wx * 32 + nt * 16 + l16) * 128 + kk * 64 + quad * 16);
#pragma unroll
        for (int kk = 0; kk < 2; kk++)
#pragma unroll
            for (int mt = 0; mt < 4; mt++)
#pragma unroll
                for (int nt = 0; nt < 2; nt++)
                    acc[mt][nt] = __builtin_amdgcn_mfma_f32_16x16x32_bf16(
                        af[mt][kk], bfr[nt][kk], acc[mt][nt], 0, 0, 0);
        __syncthreads();
    }

#pragma unroll
    for (int mt = 0; mt < 4; mt++) {
#pragma unroll
        for (int nt = 0; nt < 2; nt++) {
            int gn = col0 + wx * 32 + nt * 16 + l16;
            int gmb = row0 + wy * 64 + mt * 16 + quad * 4;
#pragma unroll
            for (int r = 0; r < 4; r++) {
                int gm = gmb + r;
                if (gm < M) {
                    if (OUTM == 0) {
                        ((__hip_bfloat16*)C)[(size_t)gm * Npitch + gn] =
                            __float2bfloat16(acc[mt][nt][r]);
                    } else {
                        float v = acc[mt][nt][r];
                        int p = __builtin_amdgcn_cvt_pk_fp8_f32(v, v, 0, false);
                        ((unsigned char*)C)[(size_t)gm * Npitch + gn] =
                            (unsigned char)(p & 0xff);
                    }
                }
            }
        }
    }
}

// ---------------- SpMM L1: fp8 support (D=256), bias+relu, bf16 out --------
// G=16 lanes/edge-group x 16B uintx4 gathers (16 fp8 each); 4 groups x U=4
// = 16 edges in flight/wave. HW v_cvt_pk_f32_fp8 decode (2 floats/instr).
// Edge index clamped inside the row (cached re-read, no junk fetch).

__global__ __launch_bounds__(256) void spmm_fp8_256(const int* __restrict__ row_ptr,
                                                    const unsigned int* __restrict__ edge_pk,
                                                    const unsigned char* __restrict__ sup8,
                                                    const float* __restrict__ bias,
                                                    __hip_bfloat16* __restrict__ out,
                                                    int n_nodes) {
    constexpr int G = 16, U = 4, CH = (64 / G) * U;   // 16 edges/iter
    int node = blockIdx.x * (256 / WAVE) + (threadIdx.x >> 6);
    if (node >= n_nodes) return;
    node = __builtin_amdgcn_readfirstlane(node);
    const int lane = threadIdx.x & 63;
    const int g = lane >> 4;             // edge-group id (0..3)
    const int t = lane & 15;             // owns cols [t*16, t*16+16)
    int e = row_ptr[node];
    const int end = row_ptr[node + 1];
    const unsigned char* sup = sup8 + t * 16;

    float acc[16];
#pragma unroll
    for (int i = 0; i < 16; i++) acc[i] = 0.f;

    while (e < end) {
        const int base = e + g * U;
        unsigned int pk[U];
#pragma unroll
        for (int u = 0; u < U; u++) {
            int idx = base + u;
            if (idx > end - 1) idx = end - 1;   // clamp INSIDE row
            pk[u] = edge_pk[idx];
        }
        uintx4 v[U];
#pragma unroll
        for (int u = 0; u < U; u++)
            v[u] = *(const uintx4*)(sup + (size_t)(pk[u] >> 15) * 256);
#pragma unroll
        for (int u = 0; u < U; u++) {
            float wq = (float)(pk[u] & 0x7fffu) * (1.f / 32767.f);
            float wt = (base + u < end) ? wq : 0.f;
#pragma unroll
            for (int d = 0; d < 4; d++) {
                floatx2 lo = __builtin_amdgcn_cvt_pk_f32_fp8(v[u][d], false);
                floatx2 hi = __builtin_amdgcn_cvt_pk_f32_fp8(v[u][d], true);
                acc[d * 4 + 0] += lo[0] * wt;
                acc[d * 4 + 1] += lo[1] * wt;
                acc[d * 4 + 2] += hi[0] * wt;
                acc[d * 4 + 3] += hi[1] * wt;
            }
        }
        e += CH;
    }

    // merge the 4 edge-groups: butterfly over lane bits 4,5
#pragma unroll
    for (int off = 16; off < 64; off <<= 1)
#pragma unroll
        for (int i = 0; i < 16; i++) acc[i] += __shfl_xor(acc[i], off);

    if (lane < 16) {
        ushort8 o0, o1;
#pragma unroll
        for (int i = 0; i < 8; i++) {
            float r0 = acc[i] + bias[t * 16 + i];
            float r1 = acc[8 + i] + bias[t * 16 + 8 + i];
            r0 = r0 > 0.f ? r0 : 0.f;
            r1 = r1 > 0.f ? r1 : 0.f;
            __hip_bfloat16 b0 = __float2bfloat16(r0);
            __hip_bfloat16 b1 = __float2bfloat16(r1);
            o0[i] = *(unsigned short*)&b0;
            o1[i] = *(unsigned short*)&b1;
        }
        union { ushort8 s; uintx4 u; } c0, c1; c0.s = o0; c1.s = o1;
        unsigned short* op = (unsigned short*)out + (size_t)node * 256 + t * 16;
        __builtin_nontemporal_store(c0.u, (uintx4*)op);
        __builtin_nontemporal_store(c1.u, (uintx4*)(op + 8));
    }
}

// ---------------- SpMM (CSR by dst) + bias + relu, bf16 gathers -------------
// v3: one wave per dst node; lanes split into 64/G groups of G lanes; each
// group owns one edge at a time and gathers its support row as G x 16B
// (ushort8) loads; U rounds unrolled => (64/G)*U edges in flight per wave.
// Edge index is CLAMPED to the row's last edge (tail gathers hit the same
// already-cached row -> no junk fetch; tail weight forced to 0).
// After the row, a shfl_xor butterfly over offsets {G..32} merges the group
// partials. FINAL=true fuses log_softmax over the 40 real classes
// (support pitch 64; pad cols are exactly zero) and writes fp32 [n,40].

template <int D, int G, int U, bool FINAL, typename OT>
__global__ __launch_bounds__(256) void spmm_bias_relu(const int* __restrict__ row_ptr,
                                                      const unsigned int* __restrict__ edge_pk,
                                                      const __hip_bfloat16* __restrict__ support,
                                                      const float* __restrict__ bias,
                                                      OT* __restrict__ out,
                                                      int n_nodes) {
    constexpr int NG = 64 / G;           // edge groups per wave
    constexpr int CH = NG * U;           // edges consumed per iteration
    int node = blockIdx.x * (256 / WAVE) + (threadIdx.x >> 6);
    if (node >= n_nodes) return;
    node = __builtin_amdgcn_readfirstlane(node);
    const int lane = threadIdx.x & 63;
    const int g = lane / G;              // edge-group id
    const int t = lane & (G - 1);        // lane-in-group: owns cols [t*8, t*8+8)
    int e = row_ptr[node];
    const int end = row_ptr[node + 1];
    const unsigned short* sup = (const unsigned short*)support + t * 8;

    float acc[8];
#pragma unroll
    for (int i = 0; i < 8; i++) acc[i] = 0.f;

    while (e < end) {
        const int base = e + g * U;      // this group's contiguous edge chunk
        unsigned int pk[U];
#pragma unroll
        for (int u = 0; u < U; u++) {
            int idx = base + u;
            if (idx > end - 1) idx = end - 1;   // clamp INSIDE row: re-gather of
            pk[u] = edge_pk[idx];               // cached row, no junk fetch
        }
        ushort8 v[U];
#pragma unroll
        for (int u = 0; u < U; u++)
            v[u] = *(const ushort8*)(sup + (size_t)(pk[u] >> 15) * D);
#pragma unroll
        for (int u = 0; u < U; u++) {
            float wq = (float)(pk[u] & 0x7fffu) * (1.f / 32767.f);
            float wt = (base + u < end) ? wq : 0.f;   // tail contributes 0
#pragma unroll
            for (int i = 0; i < 8; i++) acc[i] += bf2f(v[u][i]) * wt;
        }
        e += CH;
    }

    // merge group partials: butterfly over group-id bits (all lanes end with
    // the full sum for their column slice)
#pragma unroll
    for (int off = G; off < 64; off <<= 1)
#pragma unroll
        for (int i = 0; i < 8; i++) acc[i] += __shfl_xor(acc[i], off);

    if (!FINAL) {
        ushort8 o;
#pragma unroll
        for (int i = 0; i < 8; i++) {
            float r = acc[i] + bias[t * 8 + i];
            r = r > 0.f ? r : 0.f;
            __hip_bfloat16 b = __float2bfloat16(r);
            o[i] = *(unsigned short*)&b;
        }
        if (lane < G) {
            union { ushort8 s; uintx4 u; } cvt; cvt.s = o;
            __builtin_nontemporal_store(cvt.u,
                (uintx4*)((unsigned short*)out + (size_t)node * D + t * 8));
        }
    } else {
        // D==64 pitch, 40 real classes; fused log_softmax
        float r[8];
#pragma unroll
        for (int i = 0; i < 8; i++) {
            float x = acc[i] + bias[t * 8 + i];
            r[i] = x > 0.f ? x : 0.f;
        }
        float m = -INFINITY;
#pragma unroll
        for (int i = 0; i < 8; i++)
            if (t * 8 + i < 40) m = fmaxf(m, r[i]);
#pragma unroll
        for (int off = 1; off < G; off <<= 1) m = fmaxf(m, __shfl_xor(m, off));
        float s = 0.f;
#pragma unroll
        for (int i = 0; i < 8; i++)
            if (t * 8 + i < 40) s += __expf(r[i] - m);
#pragma unroll
        for (int off = 1; off < G; off <<= 1) s += __shfl_xor(s, off);
        const float lse = __logf(s);
        if (lane < 5) {                 // lanes 0..4 cover cols 0..39
            float* op = (float*)out + (size_t)node * 40 + lane * 8;
#pragma unroll
            for (int i = 0; i < 8; i++) op[i] = r[i] - m - lse;
        }
    }
}

// ---------------- launch ----------------------------------------------------

extern "C" void kernel_launch(void* const* d_in, const int* in_sizes, int n_in,
                              void* d_out, int out_size, void* d_ws, size_t ws_size,
                              hipStream_t stream) {
    const float* x    = (const float*)d_in[0];
    const int*   esrc = (const int*)d_in[1];
    const int*   edst = (const int*)d_in[2];
    const float* ew   = (const float*)d_in[3];
    const float* Wm[4] = {(const float*)d_in[4], (const float*)d_in[6],
                          (const float*)d_in[8], (const float*)d_in[10]};
    const float* bm[4] = {(const float*)d_in[5], (const float*)d_in[7],
                          (const float*)d_in[9], (const float*)d_in[11]};
    const int NFEAT = 512;
    const int n_nodes = in_sizes[0] / NFEAT;
    const int n_edges = in_sizes[1];
    float* out = (float*)d_out;

    // --- workspace carve ---
    char* wsp = (char*)d_ws;
    size_t off = 0;
    auto alloc = [&](size_t bytes) -> void* {
        void* p = wsp + off;
        off += (bytes + 255) & ~(size_t)255;
        return p;
    };
    __hip_bfloat16* Xb = (__hip_bfloat16*)alloc((size_t)n_nodes * 512 * sizeof(__hip_bfloat16));
    __hip_bfloat16* Sb = (__hip_bfloat16*)alloc((size_t)n_nodes * 256 * sizeof(__hip_bfloat16));
    __hip_bfloat16* Hb = (__hip_bfloat16*)alloc((size_t)n_nodes * 256 * sizeof(__hip_bfloat16));
    __hip_bfloat16* Wt1 = (__hip_bfloat16*)alloc(256 * 512 * sizeof(__hip_bfloat16));
    __hip_bfloat16* Wt2 = (__hip_bfloat16*)alloc(128 * 256 * sizeof(__hip_bfloat16));
    __hip_bfloat16* Wt3 = (__hip_bfloat16*)alloc(64 * 128 * sizeof(__hip_bfloat16));
    __hip_bfloat16* Wt4 = (__hip_bfloat16*)alloc(64 * 64 * sizeof(__hip_bfloat16));
    float* b4p     = (float*)alloc(64 * sizeof(float));
    int*   row_ptr = (int*)alloc(((size_t)n_nodes + 1) * sizeof(int));
    int*   bhist   = (int*)alloc(NBK * sizeof(int));
    int*   bbase   = (int*)alloc((NBK + 1) * sizeof(int));
    int*   gcur    = (int*)alloc(NBK * sizeof(int));
    unsigned int* edge_pk = (unsigned int*)alloc((size_t)n_edges * sizeof(unsigned int));
    // E2 staging (8B/edge) aliases Hb: Hb is first written by L1 SpMM, which
    // runs after phaseB2 completes (same stream) -> safe.
    uint2* E2 = (uint2*)Hb;
    // L1 fp8 support aliases Sb (GEMM1 writes fp8 into it, SpMM1 reads it,
    // then GEMM2 overwrites the same region as bf16 -> sequential, safe).
    unsigned char* Sb8 = (unsigned char*)Sb;
    (void)ws_size;

    // --- conversions ---
    long n4 = (long)n_nodes * 512 / 4;
    convert_x_kernel<<<(int)((n4 + 255) / 256), 256, 0, stream>>>(x, Xb, n4);
    prep_weights_kernel<<<(131072 + 32768 + 8192 + 4096 + 64 + 255) / 256, 256, 0, stream>>>(
        Wm[0], Wm[1], Wm[2], Wm[3], bm[3], Wt1, Wt2, Wt3, Wt4, b4p);

    // --- CSR build (bucket-local) ---
    hipMemsetAsync(bhist, 0, NBK * sizeof(int), stream);
    int hblocks = (n_edges + CHA - 1) / CHA;
    bucket_hist<<<hblocks, 256, 0, stream>>>(edst, n_edges, bhist);
    bucket_scan<<<1, NBK, 0, stream>>>(bhist, bbase, gcur);
    scatter_phaseA<<<hblocks, 256, 0, stream>>>(esrc, edst, ew, n_edges, gcur, E2);
    scatter_phaseB2<<<NBK, 256, 0, stream>>>(E2, bbase, n_nodes, n_edges,
                                             row_ptr, edge_pk);

    // --- layers ---
    int spmm_blocks = (n_nodes + 3) / 4;
    dim3 g1(256 / 64, (n_nodes + 127) / 128);
    dim3 g2(128 / 64, (n_nodes + 127) / 128);
    dim3 g3(64 / 64, (n_nodes + 127) / 128);

    // L1: 512 -> 256 (support stored fp8 e4m3; gathers halve fetch bytes)
    gemm_bf16<1><<<g1, 256, 0, stream>>>(Xb, Wt1, Sb8, n_nodes, 512, 256);
    spmm_fp8_256<<<spmm_blocks, 256, 0, stream>>>(
        row_ptr, edge_pk, Sb8, bm[0], Hb, n_nodes);
    // L2: 256 -> 128
    gemm_bf16<0><<<g2, 256, 0, stream>>>(Hb, Wt2, Sb, n_nodes, 256, 128);
    spmm_bias_relu<128, 16, 4, false, __hip_bfloat16><<<spmm_blocks, 256, 0, stream>>>(
        row_ptr, edge_pk, Sb, bm[1], Hb, n_nodes);
    // L3: 128 -> 64
    gemm_bf16<0><<<g3, 256, 0, stream>>>(Hb, Wt3, Sb, n_nodes, 128, 64);
    spmm_bias_relu<64, 8, 2, false, __hip_bfloat16><<<spmm_blocks, 256, 0, stream>>>(
        row_ptr, edge_pk, Sb, bm[2], Hb, n_nodes);
    // L4: 64 -> 40 (N padded to 64; padded support cols/bias are zero)
    // fused log_softmax -> writes final fp32 [n,40] directly
    gemm_bf16<0><<<g3, 256, 0, stream>>>(Hb, Wt4, Sb, n_nodes, 64, 64);
    spmm_bias_relu<64, 8, 2, true, float><<<spmm_blocks, 256, 0, stream>>>(
        row_ptr, edge_pk, Sb, b4p, out, n_nodes);
}

// Round 5
// 837.874 us; speedup vs baseline: 1.4414x; 1.0310x over previous
//
#include <hip/hip_runtime.h>
#include <hip/hip_bf16.h>
#include <math.h>
#include <stdint.h>

// ---------------------------------------------------------------------------
// GCN 4-layer, mixed bf16/fp8 datapath:
//   h = relu( A_w @ (h @ W) + b ) x4, then log_softmax (fp32 out).
//   - dst-CSR built once per call; edges packed u32 (src<<15 | w*32767)
//   - CSR build is fully bucket-local (bucket = dst>>8):
//       bucket_hist (LDS 512-bin) -> bucket_scan (bbase) -> phaseA (LDS-binned
//       scatter into bucket regions) -> phaseB2 (one block per bucket: LDS
//       per-node hist + scan -> row_ptr AND exact CSR placement, LDS atomics
//       only). Global atomics: ~200K total.
//   - GEMM: bf16 MFMA 16x16x32, tile 128x64, BK=64, global_load_lds staging
//   - SpMM is FETCH-bound at ~3.55 TB/s (L2-fill path plateau, confirmed over
//     4 rounds: time == FETCH_SIZE / 3.55 TB/s). So supports for L1/L2/L3 are
//     stored fp8 e4m3 (HW cvt both ways): halves delivered bytes AND the
//     working set (better L2 hit rate). L4 support stays bf16 (feeds logits
//     directly; clean revert point).
//   - spmm_fp8<D,U>: G=D/16 lanes per edge-group, 16B uintx4 gathers (16 fp8
//     per lane), (64/G)*U = 16 edges in flight; HW v_cvt_pk_f32_fp8 decode;
//     edge index CLAMPED inside the row (cached re-read, no junk fetch);
//     shfl_xor butterfly merges groups; fused bias+relu, bf16 out.
//   - L4 (bf16) spmm fuses log_softmax (writes final fp32 [n,40] directly).
// ---------------------------------------------------------------------------

#define WAVE 64
#define NBK 512          // scatter buckets (dst >> 8); covers up to 131072 nodes
#define CHA 8192         // edges per histogram/phaseA block
typedef __attribute__((ext_vector_type(8))) short short8;
typedef __attribute__((ext_vector_type(8))) unsigned short ushort8;
typedef __attribute__((ext_vector_type(4))) unsigned int uintx4;
typedef __attribute__((ext_vector_type(4))) float floatx4;
typedef __attribute__((ext_vector_type(2))) float floatx2;

__device__ __forceinline__ void async_copy16(const void* g, void* l) {
    __builtin_amdgcn_global_load_lds(
        (const __attribute__((address_space(1))) void*)g,
        (__attribute__((address_space(3))) void*)l, 16, 0, 0);
}
__device__ __forceinline__ float bf2f(unsigned short u) {
    union { unsigned int i; float f; } x; x.i = ((unsigned int)u) << 16; return x.f;
}

// ---------------- setup conversions ----------------

__global__ __launch_bounds__(256) void convert_x_kernel(const float* __restrict__ in,
                                                        __hip_bfloat16* __restrict__ out,
                                                        long n4) {
    long i = ((long)blockIdx.x * 256 + threadIdx.x);
    if (i >= n4) return;
    const float4 v = *(const float4*)(in + i * 4);
    __hip_bfloat16* o = out + i * 4;
    o[0] = __float2bfloat16(v.x); o[1] = __float2bfloat16(v.y);
    o[2] = __float2bfloat16(v.z); o[3] = __float2bfloat16(v.w);
}

// All weight transposes + bias pad in ONE kernel (launch-gap trim).
// Segments: Wt1 131072 | Wt2 32768 | Wt3 8192 | Wt4 4096 | b4p 64
__global__ __launch_bounds__(256) void prep_weights_kernel(
        const float* __restrict__ W1, const float* __restrict__ W2,
        const float* __restrict__ W3, const float* __restrict__ W4,
        const float* __restrict__ b4,
        __hip_bfloat16* __restrict__ Wt1, __hip_bfloat16* __restrict__ Wt2,
        __hip_bfloat16* __restrict__ Wt3, __hip_bfloat16* __restrict__ Wt4,
        float* __restrict__ b4p) {
    int idx = blockIdx.x * 256 + threadIdx.x;
    if (idx < 131072) {                       // Wt1: K=512 N=256
        int n = idx >> 9, k = idx & 511;
        Wt1[idx] = __float2bfloat16(W1[(size_t)k * 256 + n]);
    } else if (idx < 131072 + 32768) {        // Wt2: K=256 N=128
        int l = idx - 131072;
        int n = l >> 8, k = l & 255;
        Wt2[l] = __float2bfloat16(W2[(size_t)k * 128 + n]);
    } else if (idx < 131072 + 32768 + 8192) { // Wt3: K=128 N=64
        int l = idx - 131072 - 32768;
        int n = l >> 7, k = l & 127;
        Wt3[l] = __float2bfloat16(W3[(size_t)k * 64 + n]);
    } else if (idx < 131072 + 32768 + 8192 + 4096) { // Wt4: K=64 N=40 pad 64
        int l = idx - 131072 - 32768 - 8192;
        int n = l >> 6, k = l & 63;
        float v = (n < 40) ? W4[(size_t)k * 40 + n] : 0.f;
        Wt4[l] = __float2bfloat16(v);
    } else if (idx < 131072 + 32768 + 8192 + 4096 + 64) {
        int l = idx - 131072 - 32768 - 8192 - 4096;
        b4p[l] = (l < 40) ? b4[l] : 0.f;
    }
}

// ---------------- CSR build (bucket-local, LDS atomics) ----------------

// Coarse 512-bin histogram of dst>>8. LDS-privatized; 512 global atomics/block.
__global__ __launch_bounds__(256) void bucket_hist(const int* __restrict__ dst,
                                                   int nE, int* __restrict__ bhist) {
    __shared__ int h[NBK];
    const int t = threadIdx.x;
    const long e0 = (long)blockIdx.x * CHA;
    const int cnt = (int)((nE - e0 < CHA) ? (nE - e0) : CHA);
    for (int i = t; i < NBK; i += 256) h[i] = 0;
    __syncthreads();
    for (int i = t; i < cnt; i += 256)
        atomicAdd(&h[dst[e0 + i] >> 8], 1);
    __syncthreads();
    for (int i = t; i < NBK; i += 256)
        if (h[i]) atomicAdd(&bhist[i], h[i]);
}

// Exclusive scan of the 512 bucket counts -> bbase[513]; seeds phaseA cursors.
__global__ __launch_bounds__(512) void bucket_scan(const int* __restrict__ bhist,
                                                   int* __restrict__ bbase,
                                                   int* __restrict__ gcur) {
    __shared__ int sm[NBK];
    const int t = threadIdx.x;
    int x = bhist[t];
    sm[t] = x;
    __syncthreads();
    for (int off = 1; off < NBK; off <<= 1) {
        int add = (t >= off) ? sm[t - off] : 0;
        __syncthreads();
        if (t >= off) sm[t] += add;
        __syncthreads();
    }
    int excl = sm[t] - x;
    bbase[t] = excl;
    gcur[t] = excl;
    if (t == NBK - 1) bbase[NBK] = sm[t];
}

// Phase A: bucket edges by dst>>8 into E2 staging (u64: .y=dst, .x=src<<15|w15).
// Per-block LDS histogram + one global reservation per (block,bucket); writes
// land as ~16-entry runs per bucket region (line-friendly).
__global__ __launch_bounds__(256) void scatter_phaseA(const int* __restrict__ src,
                                                      const int* __restrict__ dst,
                                                      const float* __restrict__ ew,
                                                      int nE,
                                                      int* __restrict__ gcur,
                                                      uint2* __restrict__ E2) {
    __shared__ int hist[NBK];
    __shared__ int cur[NBK];
    const int t = threadIdx.x;
    const long e0 = (long)blockIdx.x * CHA;
    const int cnt = (int)((nE - e0 < CHA) ? (nE - e0) : CHA);

    for (int i = t; i < NBK; i += 256) hist[i] = 0;
    __syncthreads();
    for (int i = t; i < cnt; i += 256)
        atomicAdd(&hist[dst[e0 + i] >> 8], 1);
    __syncthreads();
    for (int i = t; i < NBK; i += 256) {
        int h = hist[i];
        cur[i] = h ? atomicAdd(&gcur[i], h) : 0;   // global base for this block
    }
    __syncthreads();
    for (int i = t; i < cnt; i += 256) {
        int d = dst[e0 + i];
        unsigned int w15 = (unsigned int)(ew[e0 + i] * 32767.f + 0.5f);
        if (w15 > 32767u) w15 = 32767u;
        int pos = atomicAdd(&cur[d >> 8], 1);      // LDS atomic -> global slot
        E2[pos] = make_uint2(((unsigned int)src[e0 + i] << 15) | w15,
                             (unsigned int)d);
    }
}

// Phase B2: one block per bucket. LDS per-node (256-bin) histogram + scan of
// this bucket's E2 segment -> writes row_ptr for the bucket's nodes AND
// scatters edges to exact CSR slots with LDS-only cursors. Global traffic is
// the sequential E2 read + in-window edge_pk writes; zero global atomics.
__global__ __launch_bounds__(256) void scatter_phaseB2(const uint2* __restrict__ E2,
                                                       const int* __restrict__ bbase,
                                                       int n_nodes, int nE,
                                                       int* __restrict__ row_ptr,
                                                       unsigned int* __restrict__ edge_pk) {
    __shared__ int cnt[256];
    __shared__ int pfx[256];
    __shared__ int cur[256];
    const int b = blockIdx.x;
    const int t = threadIdx.x;
    const int s = bbase[b];
    const int e = bbase[b + 1];

    cnt[t] = 0;
    __syncthreads();
    for (int i = s + t; i < e; i += 256)
        atomicAdd(&cnt[E2[i].y & 255], 1);
    __syncthreads();
    pfx[t] = cnt[t];
    __syncthreads();
    for (int off = 1; off < 256; off <<= 1) {
        int add = (t >= off) ? pfx[t - off] : 0;
        __syncthreads();
        if (t >= off) pfx[t] += add;
        __syncthreads();
    }
    const int excl = pfx[t] - cnt[t];
    const int node = b * 256 + t;
    if (node < n_nodes) row_ptr[node] = s + excl;
    if (b == 0 && t == 0) row_ptr[n_nodes] = nE;
    cur[t] = s + excl;
    __syncthreads();
    for (int i = s + t; i < e; i += 256) {
        uint2 ed = E2[i];
        int p = atomicAdd(&cur[ed.y & 255], 1);    // LDS atomic
        edge_pk[p] = ed.x;
    }
}

// ---------------- bf16 MFMA GEMM: C[M,Npitch] = A[M,K] @ Wt[Npitch,K]^T -----
// OUTM: 0 = bf16 output, 1 = fp8 e4m3 output (HW cvt_pk_fp8_f32, RNE+sat)

template <int OUTM>
__global__ __launch_bounds__(256) void gemm_bf16(const __hip_bfloat16* __restrict__ A,
                                                 const __hip_bfloat16* __restrict__ Wt,
                                                 void* __restrict__ C,
                                                 int M, int K, int Npitch) {
    __shared__ __align__(16) __hip_bfloat16 sA[128 * 64];  // [row][k], 128B rows
    __shared__ __align__(16) __hip_bfloat16 sB[64 * 64];   // [n][k],   128B rows
    const int t = threadIdx.x;
    const int lane = t & 63;
    const int w = t >> 6;
    const int wy = w >> 1, wx = w & 1;
    const int quad = lane >> 4;
    const int l16 = lane & 15;
    const int row0 = blockIdx.y * 128;
    const int col0 = blockIdx.x * 64;

    floatx4 acc[4][2];
#pragma unroll
    for (int mt = 0; mt < 4; mt++)
#pragma unroll
        for (int nt = 0; nt < 2; nt++) acc[mt][nt] = 0;

    const int arow = t >> 3;
    const int koff = (t & 7) * 8;

    for (int k0 = 0; k0 < K; k0 += 64) {
#pragma unroll
        for (int r = 0; r < 4; r++) {
            int gm = row0 + r * 32 + arow;
            int gmc = (gm < M) ? gm : 0;
            async_copy16(A + (size_t)gmc * K + k0 + koff,
                         (char*)sA + r * 4096 + t * 16);
        }
#pragma unroll
        for (int r = 0; r < 2; r++) {
            int n = r * 32 + arow;
            async_copy16(Wt + (size_t)(col0 + n) * K + k0 + koff,
                         (char*)sB + r * 4096 + t * 16);
        }
        __syncthreads();

        short8 af[4][2], bfr[2][2];
#pragma unroll
        for (int mt = 0; mt < 4; mt++)
#pragma unroll
            for (int kk = 0; kk < 2; kk++)
                af[mt][kk] = *(const short8*)((const char*)sA +
                             (wy * 64 + mt * 16 + l16) * 128 + kk * 64 + quad * 16);
#pragma unroll
        for (int nt = 0; nt < 2; nt++)
#pragma unroll
            for (int kk = 0; kk < 2; kk++)
                bfr[nt][kk] = *(const short8*)((const char*)sB +
                              (wx * 32 + nt * 16 + l16) * 128 + kk * 64 + quad * 16);
#pragma unroll
        for (int kk = 0; kk < 2; kk++)
#pragma unroll
            for (int mt = 0; mt < 4; mt++)
#pragma unroll
                for (int nt = 0; nt < 2; nt++)
                    acc[mt][nt] = __builtin_amdgcn_mfma_f32_16x16x32_bf16(
                        af[mt][kk], bfr[nt][kk], acc[mt][nt], 0, 0, 0);
        __syncthreads();
    }

#pragma unroll
    for (int mt = 0; mt < 4; mt++) {
#pragma unroll
        for (int nt = 0; nt < 2; nt++) {
            int gn = col0 + wx * 32 + nt * 16 + l16;
            int gmb = row0 + wy * 64 + mt * 16 + quad * 4;
#pragma unroll
            for (int r = 0; r < 4; r++) {
                int gm = gmb + r;
                if (gm < M) {
                    if (OUTM == 0) {
                        ((__hip_bfloat16*)C)[(size_t)gm * Npitch + gn] =
                            __float2bfloat16(acc[mt][nt][r]);
                    } else {
                        float v = acc[mt][nt][r];
                        int p = __builtin_amdgcn_cvt_pk_fp8_f32(v, v, 0, false);
                        ((unsigned char*)C)[(size_t)gm * Npitch + gn] =
                            (unsigned char)(p & 0xff);
                    }
                }
            }
        }
    }
}

// ---------------- SpMM, fp8 support (D cols), bias + relu, bf16 out --------
// G=D/16 lanes/edge-group x 16B uintx4 gathers (16 fp8 each); (64/G)*U = 16
// edges in flight/wave. HW v_cvt_pk_f32_fp8 decode (2 floats/instr).
// Edge index clamped inside the row (cached re-read, no junk fetch).

template <int D, int U>
__global__ __launch_bounds__(256) void spmm_fp8(const int* __restrict__ row_ptr,
                                                const unsigned int* __restrict__ edge_pk,
                                                const unsigned char* __restrict__ sup8,
                                                const float* __restrict__ bias,
                                                __hip_bfloat16* __restrict__ out,
                                                int n_nodes) {
    constexpr int G = D / 16;            // lanes per edge-group
    constexpr int NG = 64 / G;           // edge groups per wave
    constexpr int CH = NG * U;           // edges consumed per iteration
    int node = blockIdx.x * (256 / WAVE) + (threadIdx.x >> 6);
    if (node >= n_nodes) return;
    node = __builtin_amdgcn_readfirstlane(node);
    const int lane = threadIdx.x & 63;
    const int g = lane / G;              // edge-group id
    const int t = lane & (G - 1);        // owns cols [t*16, t*16+16)
    int e = row_ptr[node];
    const int end = row_ptr[node + 1];
    const unsigned char* sup = sup8 + t * 16;

    float acc[16];
#pragma unroll
    for (int i = 0; i < 16; i++) acc[i] = 0.f;

    while (e < end) {
        const int base = e + g * U;
        unsigned int pk[U];
#pragma unroll
        for (int u = 0; u < U; u++) {
            int idx = base + u;
            if (idx > end - 1) idx = end - 1;   // clamp INSIDE row
            pk[u] = edge_pk[idx];
        }
        uintx4 v[U];
#pragma unroll
        for (int u = 0; u < U; u++)
            v[u] = *(const uintx4*)(sup + (size_t)(pk[u] >> 15) * D);
#pragma unroll
        for (int u = 0; u < U; u++) {
            float wq = (float)(pk[u] & 0x7fffu) * (1.f / 32767.f);
            float wt = (base + u < end) ? wq : 0.f;
#pragma unroll
            for (int d = 0; d < 4; d++) {
                floatx2 lo = __builtin_amdgcn_cvt_pk_f32_fp8(v[u][d], false);
                floatx2 hi = __builtin_amdgcn_cvt_pk_f32_fp8(v[u][d], true);
                acc[d * 4 + 0] += lo[0] * wt;
                acc[d * 4 + 1] += lo[1] * wt;
                acc[d * 4 + 2] += hi[0] * wt;
                acc[d * 4 + 3] += hi[1] * wt;
            }
        }
        e += CH;
    }

    // merge edge-groups: butterfly over group-id bits
#pragma unroll
    for (int off = G; off < 64; off <<= 1)
#pragma unroll
        for (int i = 0; i < 16; i++) acc[i] += __shfl_xor(acc[i], off);

    if (lane < G) {
        ushort8 o0, o1;
#pragma unroll
        for (int i = 0; i < 8; i++) {
            float r0 = acc[i] + bias[t * 16 + i];
            float r1 = acc[8 + i] + bias[t * 16 + 8 + i];
            r0 = r0 > 0.f ? r0 : 0.f;
            r1 = r1 > 0.f ? r1 : 0.f;
            __hip_bfloat16 b0 = __float2bfloat16(r0);
            __hip_bfloat16 b1 = __float2bfloat16(r1);
            o0[i] = *(unsigned short*)&b0;
            o1[i] = *(unsigned short*)&b1;
        }
        union { ushort8 s; uintx4 u; } c0, c1; c0.s = o0; c1.s = o1;
        unsigned short* op = (unsigned short*)out + (size_t)node * D + t * 16;
        __builtin_nontemporal_store(c0.u, (uintx4*)op);
        __builtin_nontemporal_store(c1.u, (uintx4*)(op + 8));
    }
}

// ---------------- SpMM (CSR by dst) + bias + relu, bf16 gathers -------------
// v3: one wave per dst node; lanes split into 64/G groups of G lanes; each
// group owns one edge at a time and gathers its support row as G x 16B
// (ushort8) loads; U rounds unrolled => (64/G)*U edges in flight per wave.
// Edge index is CLAMPED to the row's last edge (tail gathers hit the same
// already-cached row -> no junk fetch; tail weight forced to 0).
// After the row, a shfl_xor butterfly over offsets {G..32} merges the group
// partials. FINAL=true fuses log_softmax over the 40 real classes
// (support pitch 64; pad cols are exactly zero) and writes fp32 [n,40].

template <int D, int G, int U, bool FINAL, typename OT>
__global__ __launch_bounds__(256) void spmm_bias_relu(const int* __restrict__ row_ptr,
                                                      const unsigned int* __restrict__ edge_pk,
                                                      const __hip_bfloat16* __restrict__ support,
                                                      const float* __restrict__ bias,
                                                      OT* __restrict__ out,
                                                      int n_nodes) {
    constexpr int NG = 64 / G;           // edge groups per wave
    constexpr int CH = NG * U;           // edges consumed per iteration
    int node = blockIdx.x * (256 / WAVE) + (threadIdx.x >> 6);
    if (node >= n_nodes) return;
    node = __builtin_amdgcn_readfirstlane(node);
    const int lane = threadIdx.x & 63;
    const int g = lane / G;              // edge-group id
    const int t = lane & (G - 1);        // lane-in-group: owns cols [t*8, t*8+8)
    int e = row_ptr[node];
    const int end = row_ptr[node + 1];
    const unsigned short* sup = (const unsigned short*)support + t * 8;

    float acc[8];
#pragma unroll
    for (int i = 0; i < 8; i++) acc[i] = 0.f;

    while (e < end) {
        const int base = e + g * U;      // this group's contiguous edge chunk
        unsigned int pk[U];
#pragma unroll
        for (int u = 0; u < U; u++) {
            int idx = base + u;
            if (idx > end - 1) idx = end - 1;   // clamp INSIDE row: re-gather of
            pk[u] = edge_pk[idx];               // cached row, no junk fetch
        }
        ushort8 v[U];
#pragma unroll
        for (int u = 0; u < U; u++)
            v[u] = *(const ushort8*)(sup + (size_t)(pk[u] >> 15) * D);
#pragma unroll
        for (int u = 0; u < U; u++) {
            float wq = (float)(pk[u] & 0x7fffu) * (1.f / 32767.f);
            float wt = (base + u < end) ? wq : 0.f;   // tail contributes 0
#pragma unroll
            for (int i = 0; i < 8; i++) acc[i] += bf2f(v[u][i]) * wt;
        }
        e += CH;
    }

    // merge group partials: butterfly over group-id bits (all lanes end with
    // the full sum for their column slice)
#pragma unroll
    for (int off = G; off < 64; off <<= 1)
#pragma unroll
        for (int i = 0; i < 8; i++) acc[i] += __shfl_xor(acc[i], off);

    if (!FINAL) {
        ushort8 o;
#pragma unroll
        for (int i = 0; i < 8; i++) {
            float r = acc[i] + bias[t * 8 + i];
            r = r > 0.f ? r : 0.f;
            __hip_bfloat16 b = __float2bfloat16(r);
            o[i] = *(unsigned short*)&b;
        }
        if (lane < G) {
            union { ushort8 s; uintx4 u; } cvt; cvt.s = o;
            __builtin_nontemporal_store(cvt.u,
                (uintx4*)((unsigned short*)out + (size_t)node * D + t * 8));
        }
    } else {
        // D==64 pitch, 40 real classes; fused log_softmax
        float r[8];
#pragma unroll
        for (int i = 0; i < 8; i++) {
            float x = acc[i] + bias[t * 8 + i];
            r[i] = x > 0.f ? x : 0.f;
        }
        float m = -INFINITY;
#pragma unroll
        for (int i = 0; i < 8; i++)
            if (t * 8 + i < 40) m = fmaxf(m, r[i]);
#pragma unroll
        for (int off = 1; off < G; off <<= 1) m = fmaxf(m, __shfl_xor(m, off));
        float s = 0.f;
#pragma unroll
        for (int i = 0; i < 8; i++)
            if (t * 8 + i < 40) s += __expf(r[i] - m);
#pragma unroll
        for (int off = 1; off < G; off <<= 1) s += __shfl_xor(s, off);
        const float lse = __logf(s);
        if (lane < 5) {                 // lanes 0..4 cover cols 0..39
            float* op = (float*)out + (size_t)node * 40 + lane * 8;
#pragma unroll
            for (int i = 0; i < 8; i++) op[i] = r[i] - m - lse;
        }
    }
}

// ---------------- launch ----------------------------------------------------

extern "C" void kernel_launch(void* const* d_in, const int* in_sizes, int n_in,
                              void* d_out, int out_size, void* d_ws, size_t ws_size,
                              hipStream_t stream) {
    const float* x    = (const float*)d_in[0];
    const int*   esrc = (const int*)d_in[1];
    const int*   edst = (const int*)d_in[2];
    const float* ew   = (const float*)d_in[3];
    const float* Wm[4] = {(const float*)d_in[4], (const float*)d_in[6],
                          (const float*)d_in[8], (const float*)d_in[10]};
    const float* bm[4] = {(const float*)d_in[5], (const float*)d_in[7],
                          (const float*)d_in[9], (const float*)d_in[11]};
    const int NFEAT = 512;
    const int n_nodes = in_sizes[0] / NFEAT;
    const int n_edges = in_sizes[1];
    float* out = (float*)d_out;

    // --- workspace carve ---
    char* wsp = (char*)d_ws;
    size_t off = 0;
    auto alloc = [&](size_t bytes) -> void* {
        void* p = wsp + off;
        off += (bytes + 255) & ~(size_t)255;
        return p;
    };
    __hip_bfloat16* Xb = (__hip_bfloat16*)alloc((size_t)n_nodes * 512 * sizeof(__hip_bfloat16));
    __hip_bfloat16* Sb = (__hip_bfloat16*)alloc((size_t)n_nodes * 256 * sizeof(__hip_bfloat16));
    __hip_bfloat16* Hb = (__hip_bfloat16*)alloc((size_t)n_nodes * 256 * sizeof(__hip_bfloat16));
    __hip_bfloat16* Wt1 = (__hip_bfloat16*)alloc(256 * 512 * sizeof(__hip_bfloat16));
    __hip_bfloat16* Wt2 = (__hip_bfloat16*)alloc(128 * 256 * sizeof(__hip_bfloat16));
    __hip_bfloat16* Wt3 = (__hip_bfloat16*)alloc(64 * 128 * sizeof(__hip_bfloat16));
    __hip_bfloat16* Wt4 = (__hip_bfloat16*)alloc(64 * 64 * sizeof(__hip_bfloat16));
    float* b4p     = (float*)alloc(64 * sizeof(float));
    int*   row_ptr = (int*)alloc(((size_t)n_nodes + 1) * sizeof(int));
    int*   bhist   = (int*)alloc(NBK * sizeof(int));
    int*   bbase   = (int*)alloc((NBK + 1) * sizeof(int));
    int*   gcur    = (int*)alloc(NBK * sizeof(int));
    unsigned int* edge_pk = (unsigned int*)alloc((size_t)n_edges * sizeof(unsigned int));
    // E2 staging (8B/edge) aliases Hb: Hb is first written by L1 SpMM, which
    // runs after phaseB2 completes (same stream) -> safe.
    uint2* E2 = (uint2*)Hb;
    // fp8 supports alias Sb (GEMM writes fp8, spmm reads it, next GEMM
    // overwrites the same region -> sequential, safe).
    unsigned char* Sb8 = (unsigned char*)Sb;
    (void)ws_size;

    // --- conversions ---
    long n4 = (long)n_nodes * 512 / 4;
    convert_x_kernel<<<(int)((n4 + 255) / 256), 256, 0, stream>>>(x, Xb, n4);
    prep_weights_kernel<<<(131072 + 32768 + 8192 + 4096 + 64 + 255) / 256, 256, 0, stream>>>(
        Wm[0], Wm[1], Wm[2], Wm[3], bm[3], Wt1, Wt2, Wt3, Wt4, b4p);

    // --- CSR build (bucket-local) ---
    hipMemsetAsync(bhist, 0, NBK * sizeof(int), stream);
    int hblocks = (n_edges + CHA - 1) / CHA;
    bucket_hist<<<hblocks, 256, 0, stream>>>(edst, n_edges, bhist);
    bucket_scan<<<1, NBK, 0, stream>>>(bhist, bbase, gcur);
    scatter_phaseA<<<hblocks, 256, 0, stream>>>(esrc, edst, ew, n_edges, gcur, E2);
    scatter_phaseB2<<<NBK, 256, 0, stream>>>(E2, bbase, n_nodes, n_edges,
                                             row_ptr, edge_pk);

    // --- layers ---
    int spmm_blocks = (n_nodes + 3) / 4;
    dim3 g1(256 / 64, (n_nodes + 127) / 128);
    dim3 g2(128 / 64, (n_nodes + 127) / 128);
    dim3 g3(64 / 64, (n_nodes + 127) / 128);

    // L1: 512 -> 256 (support fp8 e4m3)
    gemm_bf16<1><<<g1, 256, 0, stream>>>(Xb, Wt1, Sb8, n_nodes, 512, 256);
    spmm_fp8<256, 4><<<spmm_blocks, 256, 0, stream>>>(
        row_ptr, edge_pk, Sb8, bm[0], Hb, n_nodes);
    // L2: 256 -> 128 (support fp8 e4m3)
    gemm_bf16<1><<<g2, 256, 0, stream>>>(Hb, Wt2, Sb8, n_nodes, 256, 128);
    spmm_fp8<128, 2><<<spmm_blocks, 256, 0, stream>>>(
        row_ptr, edge_pk, Sb8, bm[1], Hb, n_nodes);
    // L3: 128 -> 64 (support fp8 e4m3)
    gemm_bf16<1><<<g3, 256, 0, stream>>>(Hb, Wt3, Sb8, n_nodes, 128, 64);
    spmm_fp8<64, 1><<<spmm_blocks, 256, 0, stream>>>(
        row_ptr, edge_pk, Sb8, bm[2], Hb, n_nodes);
    // L4: 64 -> 40 (N padded to 64; support stays bf16 -> logits)
    // fused log_softmax -> writes final fp32 [n,40] directly
    gemm_bf16<0><<<g3, 256, 0, stream>>>(Hb, Wt4, Sb, n_nodes, 64, 64);
    spmm_bias_relu<64, 8, 2, true, float><<<spmm_blocks, 256, 0, stream>>>(
        row_ptr, edge_pk, Sb, b4p, out, n_nodes);
}

// Round 6
// 825.528 us; speedup vs baseline: 1.4629x; 1.0150x over previous
//
#include <hip/hip_runtime.h>
#include <hip/hip_bf16.h>
#include <math.h>
#include <stdint.h>

// ---------------------------------------------------------------------------
// GCN 4-layer, mixed bf16/fp8 datapath:
//   h = relu( A_w @ (h @ W) + b ) x4, then log_softmax (fp32 out).
//   - dst-CSR built once per call; edges packed u32 (src<<15 | w*32767)
//   - CSR build is fully bucket-local (bucket = dst>>8): bucket_hist ->
//     bucket_scan -> phaseA (LDS-binned scatter) -> phaseB2 (one block per
//     bucket: LDS per-node hist + scan -> row_ptr + exact CSR placement).
//     ~200K global atomics total.
//   - GEMM1/2: 128x128 tile, 4 waves x (4x4) 16x16x32 bf16 MFMA fragments,
//     BK=64, LDS 32KB. GEMM1 reads fp32 X directly (reg-stage A: float4 loads
//     -> cvt bf16 -> ds_write_b128), killing the separate convert kernel and
//     its 307 MB of traffic. GEMM3/4 keep the 128x64 kernel (N=64).
//   - All four supports stored fp8 e4m3 (HW cvt both ways): SpMM is
//     FETCH-bound at ~3.55 TB/s when working set >> L2, so bytes == time.
//   - spmm_fp8<D,U,FINAL>: G=D/16 lanes/edge-group, 16B uintx4 gathers,
//     (64/G)*U edges in flight; HW v_cvt_pk_f32_fp8 decode; edge index
//     CLAMPED inside the row (cached re-read, no junk fetch); shfl_xor
//     butterfly merges groups; fused bias+relu (bf16 out) or, for FINAL
//     (L4), fused log_softmax over the 40 real classes (fp32 [n,40] out).
// ---------------------------------------------------------------------------

#define WAVE 64
#define NBK 512          // scatter buckets (dst >> 8); covers up to 131072 nodes
#define CHA 8192         // edges per histogram/phaseA block
typedef __attribute__((ext_vector_type(8))) short short8;
typedef __attribute__((ext_vector_type(8))) unsigned short ushort8;
typedef __attribute__((ext_vector_type(4))) unsigned int uintx4;
typedef __attribute__((ext_vector_type(4))) float floatx4;
typedef __attribute__((ext_vector_type(2))) float floatx2;

__device__ __forceinline__ void async_copy16(const void* g, void* l) {
    __builtin_amdgcn_global_load_lds(
        (const __attribute__((address_space(1))) void*)g,
        (__attribute__((address_space(3))) void*)l, 16, 0, 0);
}

// ---------------- setup: weight transposes + bias pad (one kernel) ---------
// Segments: Wt1 131072 | Wt2 32768 | Wt3 8192 | Wt4 4096 | b4p 64
__global__ __launch_bounds__(256) void prep_weights_kernel(
        const float* __restrict__ W1, const float* __restrict__ W2,
        const float* __restrict__ W3, const float* __restrict__ W4,
        const float* __restrict__ b4,
        __hip_bfloat16* __restrict__ Wt1, __hip_bfloat16* __restrict__ Wt2,
        __hip_bfloat16* __restrict__ Wt3, __hip_bfloat16* __restrict__ Wt4,
        float* __restrict__ b4p) {
    int idx = blockIdx.x * 256 + threadIdx.x;
    if (idx < 131072) {                       // Wt1: K=512 N=256
        int n = idx >> 9, k = idx & 511;
        Wt1[idx] = __float2bfloat16(W1[(size_t)k * 256 + n]);
    } else if (idx < 131072 + 32768) {        // Wt2: K=256 N=128
        int l = idx - 131072;
        int n = l >> 8, k = l & 255;
        Wt2[l] = __float2bfloat16(W2[(size_t)k * 128 + n]);
    } else if (idx < 131072 + 32768 + 8192) { // Wt3: K=128 N=64
        int l = idx - 131072 - 32768;
        int n = l >> 7, k = l & 127;
        Wt3[l] = __float2bfloat16(W3[(size_t)k * 64 + n]);
    } else if (idx < 131072 + 32768 + 8192 + 4096) { // Wt4: K=64 N=40 pad 64
        int l = idx - 131072 - 32768 - 8192;
        int n = l >> 6, k = l & 63;
        float v = (n < 40) ? W4[(size_t)k * 40 + n] : 0.f;
        Wt4[l] = __float2bfloat16(v);
    } else if (idx < 131072 + 32768 + 8192 + 4096 + 64) {
        int l = idx - 131072 - 32768 - 8192 - 4096;
        b4p[l] = (l < 40) ? b4[l] : 0.f;
    }
}

// ---------------- CSR build (bucket-local, LDS atomics) ----------------

__global__ __launch_bounds__(256) void bucket_hist(const int* __restrict__ dst,
                                                   int nE, int* __restrict__ bhist) {
    __shared__ int h[NBK];
    const int t = threadIdx.x;
    const long e0 = (long)blockIdx.x * CHA;
    const int cnt = (int)((nE - e0 < CHA) ? (nE - e0) : CHA);
    for (int i = t; i < NBK; i += 256) h[i] = 0;
    __syncthreads();
    for (int i = t; i < cnt; i += 256)
        atomicAdd(&h[dst[e0 + i] >> 8], 1);
    __syncthreads();
    for (int i = t; i < NBK; i += 256)
        if (h[i]) atomicAdd(&bhist[i], h[i]);
}

__global__ __launch_bounds__(512) void bucket_scan(const int* __restrict__ bhist,
                                                   int* __restrict__ bbase,
                                                   int* __restrict__ gcur) {
    __shared__ int sm[NBK];
    const int t = threadIdx.x;
    int x = bhist[t];
    sm[t] = x;
    __syncthreads();
    for (int off = 1; off < NBK; off <<= 1) {
        int add = (t >= off) ? sm[t - off] : 0;
        __syncthreads();
        if (t >= off) sm[t] += add;
        __syncthreads();
    }
    int excl = sm[t] - x;
    bbase[t] = excl;
    gcur[t] = excl;
    if (t == NBK - 1) bbase[NBK] = sm[t];
}

__global__ __launch_bounds__(256) void scatter_phaseA(const int* __restrict__ src,
                                                      const int* __restrict__ dst,
                                                      const float* __restrict__ ew,
                                                      int nE,
                                                      int* __restrict__ gcur,
                                                      uint2* __restrict__ E2) {
    __shared__ int hist[NBK];
    __shared__ int cur[NBK];
    const int t = threadIdx.x;
    const long e0 = (long)blockIdx.x * CHA;
    const int cnt = (int)((nE - e0 < CHA) ? (nE - e0) : CHA);

    for (int i = t; i < NBK; i += 256) hist[i] = 0;
    __syncthreads();
    for (int i = t; i < cnt; i += 256)
        atomicAdd(&hist[dst[e0 + i] >> 8], 1);
    __syncthreads();
    for (int i = t; i < NBK; i += 256) {
        int h = hist[i];
        cur[i] = h ? atomicAdd(&gcur[i], h) : 0;   // global base for this block
    }
    __syncthreads();
    for (int i = t; i < cnt; i += 256) {
        int d = dst[e0 + i];
        unsigned int w15 = (unsigned int)(ew[e0 + i] * 32767.f + 0.5f);
        if (w15 > 32767u) w15 = 32767u;
        int pos = atomicAdd(&cur[d >> 8], 1);      // LDS atomic -> global slot
        E2[pos] = make_uint2(((unsigned int)src[e0 + i] << 15) | w15,
                             (unsigned int)d);
    }
}

__global__ __launch_bounds__(256) void scatter_phaseB2(const uint2* __restrict__ E2,
                                                       const int* __restrict__ bbase,
                                                       int n_nodes, int nE,
                                                       int* __restrict__ row_ptr,
                                                       unsigned int* __restrict__ edge_pk) {
    __shared__ int cnt[256];
    __shared__ int pfx[256];
    __shared__ int cur[256];
    const int b = blockIdx.x;
    const int t = threadIdx.x;
    const int s = bbase[b];
    const int e = bbase[b + 1];

    cnt[t] = 0;
    __syncthreads();
    for (int i = s + t; i < e; i += 256)
        atomicAdd(&cnt[E2[i].y & 255], 1);
    __syncthreads();
    pfx[t] = cnt[t];
    __syncthreads();
    for (int off = 1; off < 256; off <<= 1) {
        int add = (t >= off) ? pfx[t - off] : 0;
        __syncthreads();
        if (t >= off) pfx[t] += add;
        __syncthreads();
    }
    const int excl = pfx[t] - cnt[t];
    const int node = b * 256 + t;
    if (node < n_nodes) row_ptr[node] = s + excl;
    if (b == 0 && t == 0) row_ptr[n_nodes] = nE;
    cur[t] = s + excl;
    __syncthreads();
    for (int i = s + t; i < e; i += 256) {
        uint2 ed = E2[i];
        int p = atomicAdd(&cur[ed.y & 255], 1);    // LDS atomic
        edge_pk[p] = ed.x;
    }
}

// ---------------- 128x128 MFMA GEMM: C = A[M,K] @ Wt[Npitch,K]^T ------------
// 4 waves (2x2), each computes a 64x64 sub-tile as 4x4 16x16x32 fragments.
// AFP32: A is fp32 (reg-stage: 2x float4 load -> 8x cvt -> ds_write_b128);
//        else A is bf16 via global_load_lds.
// OUTM: 0 = bf16 output, 1 = fp8 e4m3 output (HW cvt_pk_fp8_f32).

template <int AFP32, int OUTM>
__global__ __launch_bounds__(256) void gemm128(const void* __restrict__ Av,
                                               const __hip_bfloat16* __restrict__ Wt,
                                               void* __restrict__ C,
                                               int M, int K, int Npitch) {
    __shared__ __align__(16) __hip_bfloat16 sA[128 * 64];  // [row][k], 128B rows
    __shared__ __align__(16) __hip_bfloat16 sB[128 * 64];  // [n][k],   128B rows
    const int t = threadIdx.x;
    const int lane = t & 63;
    const int w = t >> 6;
    const int wy = w >> 1, wx = w & 1;
    const int quad = lane >> 4;
    const int l16 = lane & 15;
    const int row0 = blockIdx.y * 128;
    const int col0 = blockIdx.x * 128;

    floatx4 acc[4][4];
#pragma unroll
    for (int mt = 0; mt < 4; mt++)
#pragma unroll
        for (int nt = 0; nt < 4; nt++) acc[mt][nt] = 0;

    const int arow = t >> 3;        // 0..31
    const int koff = (t & 7) * 8;   // bf16/fp32 element offset in K-tile

    for (int k0 = 0; k0 < K; k0 += 64) {
        if (AFP32) {
            float4 fa[4][2];
#pragma unroll
            for (int r = 0; r < 4; r++) {
                int gm = row0 + r * 32 + arow;
                int gmc = (gm < M) ? gm : 0;
                const float* ap = (const float*)Av + (size_t)gmc * K + k0 + koff;
                fa[r][0] = *(const float4*)ap;
                fa[r][1] = *(const float4*)(ap + 4);
            }
#pragma unroll
            for (int r = 0; r < 4; r++) {
                ushort8 pk;
#pragma unroll
                for (int i = 0; i < 4; i++) {
                    __hip_bfloat16 b0 = __float2bfloat16(((const float*)&fa[r][0])[i]);
                    __hip_bfloat16 b1 = __float2bfloat16(((const float*)&fa[r][1])[i]);
                    pk[i] = *(unsigned short*)&b0;
                    pk[4 + i] = *(unsigned short*)&b1;
                }
                *(ushort8*)((char*)sA + r * 4096 + t * 16) = pk;
            }
        } else {
#pragma unroll
            for (int r = 0; r < 4; r++) {
                int gm = row0 + r * 32 + arow;
                int gmc = (gm < M) ? gm : 0;
                async_copy16((const __hip_bfloat16*)Av + (size_t)gmc * K + k0 + koff,
                             (char*)sA + r * 4096 + t * 16);
            }
        }
#pragma unroll
        for (int r = 0; r < 4; r++) {
            int n = r * 32 + arow;
            async_copy16(Wt + (size_t)(col0 + n) * K + k0 + koff,
                         (char*)sB + r * 4096 + t * 16);
        }
        __syncthreads();

        short8 af[4][2], bfr[4][2];
#pragma unroll
        for (int mt = 0; mt < 4; mt++)
#pragma unroll
            for (int kk = 0; kk < 2; kk++)
                af[mt][kk] = *(const short8*)((const char*)sA +
                             (wy * 64 + mt * 16 + l16) * 128 + kk * 64 + quad * 16);
#pragma unroll
        for (int nt = 0; nt < 4; nt++)
#pragma unroll
            for (int kk = 0; kk < 2; kk++)
                bfr[nt][kk] = *(const short8*)((const char*)sB +
                              (wx * 64 + nt * 16 + l16) * 128 + kk * 64 + quad * 16);
#pragma unroll
        for (int kk = 0; kk < 2; kk++)
#pragma unroll
            for (int mt = 0; mt < 4; mt++)
#pragma unroll
                for (int nt = 0; nt < 4; nt++)
                    acc[mt][nt] = __builtin_amdgcn_mfma_f32_16x16x32_bf16(
                        af[mt][kk], bfr[nt][kk], acc[mt][nt], 0, 0, 0);
        __syncthreads();
    }

#pragma unroll
    for (int mt = 0; mt < 4; mt++) {
#pragma unroll
        for (int nt = 0; nt < 4; nt++) {
            int gn = col0 + wx * 64 + nt * 16 + l16;
            int gmb = row0 + wy * 64 + mt * 16 + quad * 4;
#pragma unroll
            for (int r = 0; r < 4; r++) {
                int gm = gmb + r;
                if (gm < M) {
                    if (OUTM == 0) {
                        ((__hip_bfloat16*)C)[(size_t)gm * Npitch + gn] =
                            __float2bfloat16(acc[mt][nt][r]);
                    } else {
                        float v = acc[mt][nt][r];
                        int p = __builtin_amdgcn_cvt_pk_fp8_f32(v, v, 0, false);
                        ((unsigned char*)C)[(size_t)gm * Npitch + gn] =
                            (unsigned char)(p & 0xff);
                    }
                }
            }
        }
    }
}

// ---------------- 128x64 MFMA GEMM (N=64 layers), bf16 A --------------------
// OUTM: 0 = bf16 output, 1 = fp8 e4m3 output

template <int OUTM>
__global__ __launch_bounds__(256) void gemm_bf16(const __hip_bfloat16* __restrict__ A,
                                                 const __hip_bfloat16* __restrict__ Wt,
                                                 void* __restrict__ C,
                                                 int M, int K, int Npitch) {
    __shared__ __align__(16) __hip_bfloat16 sA[128 * 64];  // [row][k], 128B rows
    __shared__ __align__(16) __hip_bfloat16 sB[64 * 64];   // [n][k],   128B rows
    const int t = threadIdx.x;
    const int lane = t & 63;
    const int w = t >> 6;
    const int wy = w >> 1, wx = w & 1;
    const int quad = lane >> 4;
    const int l16 = lane & 15;
    const int row0 = blockIdx.y * 128;
    const int col0 = blockIdx.x * 64;

    floatx4 acc[4][2];
#pragma unroll
    for (int mt = 0; mt < 4; mt++)
#pragma unroll
        for (int nt = 0; nt < 2; nt++) acc[mt][nt] = 0;

    const int arow = t >> 3;
    const int koff = (t & 7) * 8;

    for (int k0 = 0; k0 < K; k0 += 64) {
#pragma unroll
        for (int r = 0; r < 4; r++) {
            int gm = row0 + r * 32 + arow;
            int gmc = (gm < M) ? gm : 0;
            async_copy16(A + (size_t)gmc * K + k0 + koff,
                         (char*)sA + r * 4096 + t * 16);
        }
#pragma unroll
        for (int r = 0; r < 2; r++) {
            int n = r * 32 + arow;
            async_copy16(Wt + (size_t)(col0 + n) * K + k0 + koff,
                         (char*)sB + r * 4096 + t * 16);
        }
        __syncthreads();

        short8 af[4][2], bfr[2][2];
#pragma unroll
        for (int mt = 0; mt < 4; mt++)
#pragma unroll
            for (int kk = 0; kk < 2; kk++)
                af[mt][kk] = *(const short8*)((const char*)sA +
                             (wy * 64 + mt * 16 + l16) * 128 + kk * 64 + quad * 16);
#pragma unroll
        for (int nt = 0; nt < 2; nt++)
#pragma unroll
            for (int kk = 0; kk < 2; kk++)
                bfr[nt][kk] = *(const short8*)((const char*)sB +
                              (wx * 32 + nt * 16 + l16) * 128 + kk * 64 + quad * 16);
#pragma unroll
        for (int kk = 0; kk < 2; kk++)
#pragma unroll
            for (int mt = 0; mt < 4; mt++)
#pragma unroll
                for (int nt = 0; nt < 2; nt++)
                    acc[mt][nt] = __builtin_amdgcn_mfma_f32_16x16x32_bf16(
                        af[mt][kk], bfr[nt][kk], acc[mt][nt], 0, 0, 0);
        __syncthreads();
    }

#pragma unroll
    for (int mt = 0; mt < 4; mt++) {
#pragma unroll
        for (int nt = 0; nt < 2; nt++) {
            int gn = col0 + wx * 32 + nt * 16 + l16;
            int gmb = row0 + wy * 64 + mt * 16 + quad * 4;
#pragma unroll
            for (int r = 0; r < 4; r++) {
                int gm = gmb + r;
                if (gm < M) {
                    if (OUTM == 0) {
                        ((__hip_bfloat16*)C)[(size_t)gm * Npitch + gn] =
                            __float2bfloat16(acc[mt][nt][r]);
                    } else {
                        float v = acc[mt][nt][r];
                        int p = __builtin_amdgcn_cvt_pk_fp8_f32(v, v, 0, false);
                        ((unsigned char*)C)[(size_t)gm * Npitch + gn] =
                            (unsigned char)(p & 0xff);
                    }
                }
            }
        }
    }
}

// ---------------- SpMM, fp8 support (D cols), bias+relu / final softmax ----
// G=D/16 lanes/edge-group x 16B uintx4 gathers (16 fp8 each); (64/G)*U edges
// in flight/wave. HW v_cvt_pk_f32_fp8 decode. Edge index clamped inside the
// row (cached re-read, no junk fetch). FINAL (D=64): fused log_softmax over
// the 40 real classes (pad cols excluded), writes fp32 [n,40].

template <int D, int U, bool FINAL>
__global__ __launch_bounds__(256) void spmm_fp8(const int* __restrict__ row_ptr,
                                                const unsigned int* __restrict__ edge_pk,
                                                const unsigned char* __restrict__ sup8,
                                                const float* __restrict__ bias,
                                                void* __restrict__ out,
                                                int n_nodes) {
    constexpr int G = D / 16;            // lanes per edge-group
    constexpr int NG = 64 / G;           // edge groups per wave
    constexpr int CH = NG * U;           // edges consumed per iteration
    int node = blockIdx.x * (256 / WAVE) + (threadIdx.x >> 6);
    if (node >= n_nodes) return;
    node = __builtin_amdgcn_readfirstlane(node);
    const int lane = threadIdx.x & 63;
    const int g = lane / G;              // edge-group id
    const int t = lane & (G - 1);        // owns cols [t*16, t*16+16)
    int e = row_ptr[node];
    const int end = row_ptr[node + 1];
    const unsigned char* sup = sup8 + t * 16;

    float acc[16];
#pragma unroll
    for (int i = 0; i < 16; i++) acc[i] = 0.f;

    while (e < end) {
        const int base = e + g * U;
        unsigned int pk[U];
#pragma unroll
        for (int u = 0; u < U; u++) {
            int idx = base + u;
            if (idx > end - 1) idx = end - 1;   // clamp INSIDE row
            pk[u] = edge_pk[idx];
        }
        uintx4 v[U];
#pragma unroll
        for (int u = 0; u < U; u++)
            v[u] = *(const uintx4*)(sup + (size_t)(pk[u] >> 15) * D);
#pragma unroll
        for (int u = 0; u < U; u++) {
            float wq = (float)(pk[u] & 0x7fffu) * (1.f / 32767.f);
            float wt = (base + u < end) ? wq : 0.f;
#pragma unroll
            for (int d = 0; d < 4; d++) {
                floatx2 lo = __builtin_amdgcn_cvt_pk_f32_fp8(v[u][d], false);
                floatx2 hi = __builtin_amdgcn_cvt_pk_f32_fp8(v[u][d], true);
                acc[d * 4 + 0] += lo[0] * wt;
                acc[d * 4 + 1] += lo[1] * wt;
                acc[d * 4 + 2] += hi[0] * wt;
                acc[d * 4 + 3] += hi[1] * wt;
            }
        }
        e += CH;
    }

    // merge edge-groups: butterfly over group-id bits
#pragma unroll
    for (int off = G; off < 64; off <<= 1)
#pragma unroll
        for (int i = 0; i < 16; i++) acc[i] += __shfl_xor(acc[i], off);

    if (!FINAL) {
        if (lane < G) {
            ushort8 o0, o1;
#pragma unroll
            for (int i = 0; i < 8; i++) {
                float r0 = acc[i] + bias[t * 16 + i];
                float r1 = acc[8 + i] + bias[t * 16 + 8 + i];
                r0 = r0 > 0.f ? r0 : 0.f;
                r1 = r1 > 0.f ? r1 : 0.f;
                __hip_bfloat16 b0 = __float2bfloat16(r0);
                __hip_bfloat16 b1 = __float2bfloat16(r1);
                o0[i] = *(unsigned short*)&b0;
                o1[i] = *(unsigned short*)&b1;
            }
            union { ushort8 s; uintx4 u; } c0, c1; c0.s = o0; c1.s = o1;
            unsigned short* op = (unsigned short*)out + (size_t)node * D + t * 16;
            __builtin_nontemporal_store(c0.u, (uintx4*)op);
            __builtin_nontemporal_store(c1.u, (uintx4*)(op + 8));
        }
    } else {
        // D==64 pitch, 40 real classes; fused log_softmax (pad cols excluded;
        // pad support/bias are exactly zero so relu'd pads are 0 but masked).
        float r[16];
#pragma unroll
        for (int i = 0; i < 16; i++) {
            float x = acc[i] + bias[t * 16 + i];
            r[i] = x > 0.f ? x : 0.f;
        }
        float m = -INFINITY;
#pragma unroll
        for (int i = 0; i < 16; i++)
            if (t * 16 + i < 40) m = fmaxf(m, r[i]);
#pragma unroll
        for (int off = 1; off < G; off <<= 1) m = fmaxf(m, __shfl_xor(m, off));
        float s = 0.f;
#pragma unroll
        for (int i = 0; i < 16; i++)
            if (t * 16 + i < 40) s += __expf(r[i] - m);
#pragma unroll
        for (int off = 1; off < G; off <<= 1) s += __shfl_xor(s, off);
        const float lse = __logf(s);
        if (lane < G) {
            float* op = (float*)out + (size_t)node * 40;
#pragma unroll
            for (int i = 0; i < 16; i++) {
                int c = t * 16 + i;
                if (c < 40) op[c] = r[i] - m - lse;
            }
        }
    }
}

// ---------------- launch ----------------------------------------------------

extern "C" void kernel_launch(void* const* d_in, const int* in_sizes, int n_in,
                              void* d_out, int out_size, void* d_ws, size_t ws_size,
                              hipStream_t stream) {
    const float* x    = (const float*)d_in[0];
    const int*   esrc = (const int*)d_in[1];
    const int*   edst = (const int*)d_in[2];
    const float* ew   = (const float*)d_in[3];
    const float* Wm[4] = {(const float*)d_in[4], (const float*)d_in[6],
                          (const float*)d_in[8], (const float*)d_in[10]};
    const float* bm[4] = {(const float*)d_in[5], (const float*)d_in[7],
                          (const float*)d_in[9], (const float*)d_in[11]};
    const int NFEAT = 512;
    const int n_nodes = in_sizes[0] / NFEAT;
    const int n_edges = in_sizes[1];
    float* out = (float*)d_out;

    // --- workspace carve ---
    char* wsp = (char*)d_ws;
    size_t off = 0;
    auto alloc = [&](size_t bytes) -> void* {
        void* p = wsp + off;
        off += (bytes + 255) & ~(size_t)255;
        return p;
    };
    __hip_bfloat16* Sb = (__hip_bfloat16*)alloc((size_t)n_nodes * 256 * sizeof(__hip_bfloat16));
    __hip_bfloat16* Hb = (__hip_bfloat16*)alloc((size_t)n_nodes * 256 * sizeof(__hip_bfloat16));
    __hip_bfloat16* Wt1 = (__hip_bfloat16*)alloc(256 * 512 * sizeof(__hip_bfloat16));
    __hip_bfloat16* Wt2 = (__hip_bfloat16*)alloc(128 * 256 * sizeof(__hip_bfloat16));
    __hip_bfloat16* Wt3 = (__hip_bfloat16*)alloc(64 * 128 * sizeof(__hip_bfloat16));
    __hip_bfloat16* Wt4 = (__hip_bfloat16*)alloc(64 * 64 * sizeof(__hip_bfloat16));
    float* b4p     = (float*)alloc(64 * sizeof(float));
    int*   row_ptr = (int*)alloc(((size_t)n_nodes + 1) * sizeof(int));
    int*   bhist   = (int*)alloc(NBK * sizeof(int));
    int*   bbase   = (int*)alloc((NBK + 1) * sizeof(int));
    int*   gcur    = (int*)alloc(NBK * sizeof(int));
    unsigned int* edge_pk = (unsigned int*)alloc((size_t)n_edges * sizeof(unsigned int));
    // E2 staging (8B/edge) aliases Hb: Hb is first written by L1 SpMM, which
    // runs after phaseB2 completes (same stream) -> safe.
    uint2* E2 = (uint2*)Hb;
    // fp8 supports alias Sb (GEMM writes fp8, spmm reads it, next GEMM
    // overwrites the same region -> sequential, safe).
    unsigned char* Sb8 = (unsigned char*)Sb;
    (void)ws_size;

    // --- weights prep (X is read fp32 directly by GEMM1 now) ---
    prep_weights_kernel<<<(131072 + 32768 + 8192 + 4096 + 64 + 255) / 256, 256, 0, stream>>>(
        Wm[0], Wm[1], Wm[2], Wm[3], bm[3], Wt1, Wt2, Wt3, Wt4, b4p);

    // --- CSR build (bucket-local) ---
    hipMemsetAsync(bhist, 0, NBK * sizeof(int), stream);
    int hblocks = (n_edges + CHA - 1) / CHA;
    bucket_hist<<<hblocks, 256, 0, stream>>>(edst, n_edges, bhist);
    bucket_scan<<<1, NBK, 0, stream>>>(bhist, bbase, gcur);
    scatter_phaseA<<<hblocks, 256, 0, stream>>>(esrc, edst, ew, n_edges, gcur, E2);
    scatter_phaseB2<<<NBK, 256, 0, stream>>>(E2, bbase, n_nodes, n_edges,
                                             row_ptr, edge_pk);

    // --- layers ---
    int spmm_blocks = (n_nodes + 3) / 4;
    dim3 gg1(256 / 128, (n_nodes + 127) / 128);   // 128x128 tiles
    dim3 gg2(128 / 128, (n_nodes + 127) / 128);
    dim3 g3(64 / 64, (n_nodes + 127) / 128);      // 128x64 tiles

    // L1: 512 -> 256 (A = fp32 X direct; support fp8 e4m3)
    gemm128<1, 1><<<gg1, 256, 0, stream>>>(x, Wt1, Sb8, n_nodes, 512, 256);
    spmm_fp8<256, 4, false><<<spmm_blocks, 256, 0, stream>>>(
        row_ptr, edge_pk, Sb8, bm[0], Hb, n_nodes);
    // L2: 256 -> 128 (support fp8 e4m3)
    gemm128<0, 1><<<gg2, 256, 0, stream>>>(Hb, Wt2, Sb8, n_nodes, 256, 128);
    spmm_fp8<128, 2, false><<<spmm_blocks, 256, 0, stream>>>(
        row_ptr, edge_pk, Sb8, bm[1], Hb, n_nodes);
    // L3: 128 -> 64 (support fp8 e4m3)
    gemm_bf16<1><<<g3, 256, 0, stream>>>(Hb, Wt3, Sb8, n_nodes, 128, 64);
    spmm_fp8<64, 1, false><<<spmm_blocks, 256, 0, stream>>>(
        row_ptr, edge_pk, Sb8, bm[2], Hb, n_nodes);
    // L4: 64 -> 40 (N padded to 64; support fp8 e4m3; fused log_softmax
    // writes final fp32 [n,40] directly)
    gemm_bf16<1><<<g3, 256, 0, stream>>>(Hb, Wt4, Sb8, n_nodes, 64, 64);
    spmm_fp8<64, 1, true><<<spmm_blocks, 256, 0, stream>>>(
        row_ptr, edge_pk, Sb8, b4p, out, n_nodes);
}

// Round 7
// 817.735 us; speedup vs baseline: 1.4769x; 1.0095x over previous
//
#include <hip/hip_runtime.h>
#include <hip/hip_bf16.h>
#include <math.h>
#include <stdint.h>

// ---------------------------------------------------------------------------
// GCN 4-layer, mixed bf16/fp8 datapath:
//   h = relu( A_w @ (h @ W) + b ) x4, then log_softmax (fp32 out).
//   - dst-CSR built once per call; edges packed u32 (src<<15 | w*32767)
//   - CSR build is fully bucket-local (bucket = dst>>8): bucket_hist ->
//     bucket_scan -> phaseA (LDS-binned scatter) -> phaseB2 (one block per
//     bucket: LDS per-node hist + scan -> row_ptr + exact CSR placement).
//     ~200K global atomics total.
//   - GEMM1/2: 128x128 tile, 4 waves x (4x4) 16x16x32 bf16 MFMA fragments,
//     BK=64, LDS 32KB. GEMM1 reads fp32 X directly with:
//       (a) bijective XCD-chunk swizzle (col-tiles of a row-tile run on the
//           SAME XCD -> A row-tile L2-missed once, not twice: 410->205 MB)
//       (b) A-register prefetch: next K-tile's float4 loads issued after the
//           staging barrier, drained by the post-MFMA barrier -> HBM latency
//           hides under MFMA instead of serializing the staging phase.
//   - All four supports stored fp8 e4m3 (HW cvt both ways): SpMM is
//     FETCH-bound at ~3.55 TB/s beyond-L2, so bytes == time.
//   - spmm_fp8<D,U,FINAL>: G=D/16 lanes/edge-group, 16B uintx4 gathers,
//     (64/G)*U edges in flight; HW v_cvt_pk_f32_fp8 decode; edge index
//     CLAMPED inside the row (cached re-read, no junk fetch); shfl_xor
//     butterfly merges groups; fused bias+relu (bf16 out) or, for FINAL
//     (L4), fused log_softmax over the 40 real classes (fp32 [n,40] out).
// ---------------------------------------------------------------------------

#define WAVE 64
#define NBK 512          // scatter buckets (dst >> 8); covers up to 131072 nodes
#define CHA 8192         // edges per histogram/phaseA block
typedef __attribute__((ext_vector_type(8))) short short8;
typedef __attribute__((ext_vector_type(8))) unsigned short ushort8;
typedef __attribute__((ext_vector_type(4))) unsigned int uintx4;
typedef __attribute__((ext_vector_type(4))) float floatx4;
typedef __attribute__((ext_vector_type(2))) float floatx2;

__device__ __forceinline__ void async_copy16(const void* g, void* l) {
    __builtin_amdgcn_global_load_lds(
        (const __attribute__((address_space(1))) void*)g,
        (__attribute__((address_space(3))) void*)l, 16, 0, 0);
}

// ---------------- setup: weight transposes + bias pad (one kernel) ---------
// Segments: Wt1 131072 | Wt2 32768 | Wt3 8192 | Wt4 4096 | b4p 64
__global__ __launch_bounds__(256) void prep_weights_kernel(
        const float* __restrict__ W1, const float* __restrict__ W2,
        const float* __restrict__ W3, const float* __restrict__ W4,
        const float* __restrict__ b4,
        __hip_bfloat16* __restrict__ Wt1, __hip_bfloat16* __restrict__ Wt2,
        __hip_bfloat16* __restrict__ Wt3, __hip_bfloat16* __restrict__ Wt4,
        float* __restrict__ b4p) {
    int idx = blockIdx.x * 256 + threadIdx.x;
    if (idx < 131072) {                       // Wt1: K=512 N=256
        int n = idx >> 9, k = idx & 511;
        Wt1[idx] = __float2bfloat16(W1[(size_t)k * 256 + n]);
    } else if (idx < 131072 + 32768) {        // Wt2: K=256 N=128
        int l = idx - 131072;
        int n = l >> 8, k = l & 255;
        Wt2[l] = __float2bfloat16(W2[(size_t)k * 128 + n]);
    } else if (idx < 131072 + 32768 + 8192) { // Wt3: K=128 N=64
        int l = idx - 131072 - 32768;
        int n = l >> 7, k = l & 127;
        Wt3[l] = __float2bfloat16(W3[(size_t)k * 64 + n]);
    } else if (idx < 131072 + 32768 + 8192 + 4096) { // Wt4: K=64 N=40 pad 64
        int l = idx - 131072 - 32768 - 8192;
        int n = l >> 6, k = l & 63;
        float v = (n < 40) ? W4[(size_t)k * 40 + n] : 0.f;
        Wt4[l] = __float2bfloat16(v);
    } else if (idx < 131072 + 32768 + 8192 + 4096 + 64) {
        int l = idx - 131072 - 32768 - 8192 - 4096;
        b4p[l] = (l < 40) ? b4[l] : 0.f;
    }
}

// ---------------- CSR build (bucket-local, LDS atomics) ----------------

__global__ __launch_bounds__(256) void bucket_hist(const int* __restrict__ dst,
                                                   int nE, int* __restrict__ bhist) {
    __shared__ int h[NBK];
    const int t = threadIdx.x;
    const long e0 = (long)blockIdx.x * CHA;
    const int cnt = (int)((nE - e0 < CHA) ? (nE - e0) : CHA);
    for (int i = t; i < NBK; i += 256) h[i] = 0;
    __syncthreads();
    for (int i = t; i < cnt; i += 256)
        atomicAdd(&h[dst[e0 + i] >> 8], 1);
    __syncthreads();
    for (int i = t; i < NBK; i += 256)
        if (h[i]) atomicAdd(&bhist[i], h[i]);
}

__global__ __launch_bounds__(512) void bucket_scan(const int* __restrict__ bhist,
                                                   int* __restrict__ bbase,
                                                   int* __restrict__ gcur) {
    __shared__ int sm[NBK];
    const int t = threadIdx.x;
    int x = bhist[t];
    sm[t] = x;
    __syncthreads();
    for (int off = 1; off < NBK; off <<= 1) {
        int add = (t >= off) ? sm[t - off] : 0;
        __syncthreads();
        if (t >= off) sm[t] += add;
        __syncthreads();
    }
    int excl = sm[t] - x;
    bbase[t] = excl;
    gcur[t] = excl;
    if (t == NBK - 1) bbase[NBK] = sm[t];
}

__global__ __launch_bounds__(256) void scatter_phaseA(const int* __restrict__ src,
                                                      const int* __restrict__ dst,
                                                      const float* __restrict__ ew,
                                                      int nE,
                                                      int* __restrict__ gcur,
                                                      uint2* __restrict__ E2) {
    __shared__ int hist[NBK];
    __shared__ int cur[NBK];
    const int t = threadIdx.x;
    const long e0 = (long)blockIdx.x * CHA;
    const int cnt = (int)((nE - e0 < CHA) ? (nE - e0) : CHA);

    for (int i = t; i < NBK; i += 256) hist[i] = 0;
    __syncthreads();
    for (int i = t; i < cnt; i += 256)
        atomicAdd(&hist[dst[e0 + i] >> 8], 1);
    __syncthreads();
    for (int i = t; i < NBK; i += 256) {
        int h = hist[i];
        cur[i] = h ? atomicAdd(&gcur[i], h) : 0;   // global base for this block
    }
    __syncthreads();
    for (int i = t; i < cnt; i += 256) {
        int d = dst[e0 + i];
        unsigned int w15 = (unsigned int)(ew[e0 + i] * 32767.f + 0.5f);
        if (w15 > 32767u) w15 = 32767u;
        int pos = atomicAdd(&cur[d >> 8], 1);      // LDS atomic -> global slot
        E2[pos] = make_uint2(((unsigned int)src[e0 + i] << 15) | w15,
                             (unsigned int)d);
    }
}

__global__ __launch_bounds__(256) void scatter_phaseB2(const uint2* __restrict__ E2,
                                                       const int* __restrict__ bbase,
                                                       int n_nodes, int nE,
                                                       int* __restrict__ row_ptr,
                                                       unsigned int* __restrict__ edge_pk) {
    __shared__ int cnt[256];
    __shared__ int pfx[256];
    __shared__ int cur[256];
    const int b = blockIdx.x;
    const int t = threadIdx.x;
    const int s = bbase[b];
    const int e = bbase[b + 1];

    cnt[t] = 0;
    __syncthreads();
    for (int i = s + t; i < e; i += 256)
        atomicAdd(&cnt[E2[i].y & 255], 1);
    __syncthreads();
    pfx[t] = cnt[t];
    __syncthreads();
    for (int off = 1; off < 256; off <<= 1) {
        int add = (t >= off) ? pfx[t - off] : 0;
        __syncthreads();
        if (t >= off) pfx[t] += add;
        __syncthreads();
    }
    const int excl = pfx[t] - cnt[t];
    const int node = b * 256 + t;
    if (node < n_nodes) row_ptr[node] = s + excl;
    if (b == 0 && t == 0) row_ptr[n_nodes] = nE;
    cur[t] = s + excl;
    __syncthreads();
    for (int i = s + t; i < e; i += 256) {
        uint2 ed = E2[i];
        int p = atomicAdd(&cur[ed.y & 255], 1);    // LDS atomic
        edge_pk[p] = ed.x;
    }
}

// ---------------- 128x128 MFMA GEMM: C = A[M,K] @ Wt[Npitch,K]^T ------------
// 4 waves (2x2), each computes a 64x64 sub-tile as 4x4 16x16x32 fragments.
// Bijective XCD-chunk swizzle: flat wg-id -> logical id so each XCD owns a
// contiguous run of logical blocks; logical is row-major (col fastest), so
// all col-tiles of one row-tile run on ONE XCD -> A row-tile fetched once.
// AFP32: A is fp32, reg-staged (float4 -> cvt -> ds_write_b128) with
// NEXT-K-tile register prefetch issued before the MFMA cluster (latency
// drains at the post-MFMA barrier, hidden under compute).
// OUTM: 0 = bf16 output, 1 = fp8 e4m3 output (HW cvt_pk_fp8_f32).

template <int AFP32, int OUTM>
__global__ __launch_bounds__(256) void gemm128(const void* __restrict__ Av,
                                               const __hip_bfloat16* __restrict__ Wt,
                                               void* __restrict__ C,
                                               int M, int K, int Npitch) {
    __shared__ __align__(16) __hip_bfloat16 sA[128 * 64];  // [row][k], 128B rows
    __shared__ __align__(16) __hip_bfloat16 sB[128 * 64];  // [n][k],   128B rows
    const int t = threadIdx.x;
    const int lane = t & 63;
    const int w = t >> 6;
    const int wy = w >> 1, wx = w & 1;
    const int quad = lane >> 4;
    const int l16 = lane & 15;

    // XCD-bijective swizzle (m204 variant); assumes wg->XCD ~ flat%8.
    const int nwg = (int)(gridDim.x * gridDim.y);
    const int flat = (int)(blockIdx.y * gridDim.x + blockIdx.x);
    const int q = nwg >> 3, r = nwg & 7;
    const int xcd = flat & 7, pos = flat >> 3;
    const int logical = (xcd < r ? xcd * (q + 1) : r * (q + 1) + (xcd - r) * q) + pos;
    const int row0 = (logical / (int)gridDim.x) * 128;
    const int col0 = (logical % (int)gridDim.x) * 128;

    floatx4 acc[4][4];
#pragma unroll
    for (int mt = 0; mt < 4; mt++)
#pragma unroll
        for (int nt = 0; nt < 4; nt++) acc[mt][nt] = 0;

    const int arow = t >> 3;        // 0..31
    const int koff = (t & 7) * 8;   // bf16/fp32 element offset in K-tile

    float4 fa[4][2];                // fp32 A prefetch registers
    auto loadA = [&](int k0) {
#pragma unroll
        for (int rr = 0; rr < 4; rr++) {
            int gm = row0 + rr * 32 + arow;
            int gmc = (gm < M) ? gm : 0;
            const float* ap = (const float*)Av + (size_t)gmc * K + k0 + koff;
            fa[rr][0] = *(const float4*)ap;
            fa[rr][1] = *(const float4*)(ap + 4);
        }
    };
    if (AFP32) loadA(0);

    for (int k0 = 0; k0 < K; k0 += 64) {
        // B DMA first: in flight while A is converted/written.
#pragma unroll
        for (int rr = 0; rr < 4; rr++) {
            int n = rr * 32 + arow;
            async_copy16(Wt + (size_t)(col0 + n) * K + k0 + koff,
                         (char*)sB + rr * 4096 + t * 16);
        }
        if (AFP32) {
#pragma unroll
            for (int rr = 0; rr < 4; rr++) {
                ushort8 pk;
#pragma unroll
                for (int i = 0; i < 4; i++) {
                    __hip_bfloat16 b0 = __float2bfloat16(((const float*)&fa[rr][0])[i]);
                    __hip_bfloat16 b1 = __float2bfloat16(((const float*)&fa[rr][1])[i]);
                    pk[i] = *(unsigned short*)&b0;
                    pk[4 + i] = *(unsigned short*)&b1;
                }
                *(ushort8*)((char*)sA + rr * 4096 + t * 16) = pk;
            }
        } else {
#pragma unroll
            for (int rr = 0; rr < 4; rr++) {
                int gm = row0 + rr * 32 + arow;
                int gmc = (gm < M) ? gm : 0;
                async_copy16((const __hip_bfloat16*)Av + (size_t)gmc * K + k0 + koff,
                             (char*)sA + rr * 4096 + t * 16);
            }
        }
        __syncthreads();

        // Prefetch next A tile NOW: loads stay in flight across the MFMA
        // cluster and drain at the loop-end barrier (hidden latency).
        if (AFP32 && k0 + 64 < K) loadA(k0 + 64);

        short8 af[4][2], bfr[4][2];
#pragma unroll
        for (int mt = 0; mt < 4; mt++)
#pragma unroll
            for (int kk = 0; kk < 2; kk++)
                af[mt][kk] = *(const short8*)((const char*)sA +
                             (wy * 64 + mt * 16 + l16) * 128 + kk * 64 + quad * 16);
#pragma unroll
        for (int nt = 0; nt < 4; nt++)
#pragma unroll
            for (int kk = 0; kk < 2; kk++)
                bfr[nt][kk] = *(const short8*)((const char*)sB +
                              (wx * 64 + nt * 16 + l16) * 128 + kk * 64 + quad * 16);
#pragma unroll
        for (int kk = 0; kk < 2; kk++)
#pragma unroll
            for (int mt = 0; mt < 4; mt++)
#pragma unroll
                for (int nt = 0; nt < 4; nt++)
                    acc[mt][nt] = __builtin_amdgcn_mfma_f32_16x16x32_bf16(
                        af[mt][kk], bfr[nt][kk], acc[mt][nt], 0, 0, 0);
        __syncthreads();
    }

#pragma unroll
    for (int mt = 0; mt < 4; mt++) {
#pragma unroll
        for (int nt = 0; nt < 4; nt++) {
            int gn = col0 + wx * 64 + nt * 16 + l16;
            int gmb = row0 + wy * 64 + mt * 16 + quad * 4;
#pragma unroll
            for (int rr = 0; rr < 4; rr++) {
                int gm = gmb + rr;
                if (gm < M) {
                    if (OUTM == 0) {
                        ((__hip_bfloat16*)C)[(size_t)gm * Npitch + gn] =
                            __float2bfloat16(acc[mt][nt][rr]);
                    } else {
                        float v = acc[mt][nt][rr];
                        int p = __builtin_amdgcn_cvt_pk_fp8_f32(v, v, 0, false);
                        ((unsigned char*)C)[(size_t)gm * Npitch + gn] =
                            (unsigned char)(p & 0xff);
                    }
                }
            }
        }
    }
}

// ---------------- 128x64 MFMA GEMM (N=64 layers), bf16 A --------------------
// OUTM: 0 = bf16 output, 1 = fp8 e4m3 output

template <int OUTM>
__global__ __launch_bounds__(256) void gemm_bf16(const __hip_bfloat16* __restrict__ A,
                                                 const __hip_bfloat16* __restrict__ Wt,
                                                 void* __restrict__ C,
                                                 int M, int K, int Npitch) {
    __shared__ __align__(16) __hip_bfloat16 sA[128 * 64];  // [row][k], 128B rows
    __shared__ __align__(16) __hip_bfloat16 sB[64 * 64];   // [n][k],   128B rows
    const int t = threadIdx.x;
    const int lane = t & 63;
    const int w = t >> 6;
    const int wy = w >> 1, wx = w & 1;
    const int quad = lane >> 4;
    const int l16 = lane & 15;
    const int row0 = blockIdx.y * 128;
    const int col0 = blockIdx.x * 64;

    floatx4 acc[4][2];
#pragma unroll
    for (int mt = 0; mt < 4; mt++)
#pragma unroll
        for (int nt = 0; nt < 2; nt++) acc[mt][nt] = 0;

    const int arow = t >> 3;
    const int koff = (t & 7) * 8;

    for (int k0 = 0; k0 < K; k0 += 64) {
#pragma unroll
        for (int r = 0; r < 4; r++) {
            int gm = row0 + r * 32 + arow;
            int gmc = (gm < M) ? gm : 0;
            async_copy16(A + (size_t)gmc * K + k0 + koff,
                         (char*)sA + r * 4096 + t * 16);
        }
#pragma unroll
        for (int r = 0; r < 2; r++) {
            int n = r * 32 + arow;
            async_copy16(Wt + (size_t)(col0 + n) * K + k0 + koff,
                         (char*)sB + r * 4096 + t * 16);
        }
        __syncthreads();

        short8 af[4][2], bfr[2][2];
#pragma unroll
        for (int mt = 0; mt < 4; mt++)
#pragma unroll
            for (int kk = 0; kk < 2; kk++)
                af[mt][kk] = *(const short8*)((const char*)sA +
                             (wy * 64 + mt * 16 + l16) * 128 + kk * 64 + quad * 16);
#pragma unroll
        for (int nt = 0; nt < 2; nt++)
#pragma unroll
            for (int kk = 0; kk < 2; kk++)
                bfr[nt][kk] = *(const short8*)((const char*)sB +
                              (wx * 32 + nt * 16 + l16) * 128 + kk * 64 + quad * 16);
#pragma unroll
        for (int kk = 0; kk < 2; kk++)
#pragma unroll
            for (int mt = 0; mt < 4; mt++)
#pragma unroll
                for (int nt = 0; nt < 2; nt++)
                    acc[mt][nt] = __builtin_amdgcn_mfma_f32_16x16x32_bf16(
                        af[mt][kk], bfr[nt][kk], acc[mt][nt], 0, 0, 0);
        __syncthreads();
    }

#pragma unroll
    for (int mt = 0; mt < 4; mt++) {
#pragma unroll
        for (int nt = 0; nt < 2; nt++) {
            int gn = col0 + wx * 32 + nt * 16 + l16;
            int gmb = row0 + wy * 64 + mt * 16 + quad * 4;
#pragma unroll
            for (int r = 0; r < 4; r++) {
                int gm = gmb + r;
                if (gm < M) {
                    if (OUTM == 0) {
                        ((__hip_bfloat16*)C)[(size_t)gm * Npitch + gn] =
                            __float2bfloat16(acc[mt][nt][r]);
                    } else {
                        float v = acc[mt][nt][r];
                        int p = __builtin_amdgcn_cvt_pk_fp8_f32(v, v, 0, false);
                        ((unsigned char*)C)[(size_t)gm * Npitch + gn] =
                            (unsigned char)(p & 0xff);
                    }
                }
            }
        }
    }
}

// ---------------- SpMM, fp8 support (D cols), bias+relu / final softmax ----
// G=D/16 lanes/edge-group x 16B uintx4 gathers (16 fp8 each); (64/G)*U edges
// in flight/wave. HW v_cvt_pk_f32_fp8 decode. Edge index clamped inside the
// row (cached re-read, no junk fetch). FINAL (D=64): fused log_softmax over
// the 40 real classes (pad cols excluded), writes fp32 [n,40].

template <int D, int U, bool FINAL>
__global__ __launch_bounds__(256) void spmm_fp8(const int* __restrict__ row_ptr,
                                                const unsigned int* __restrict__ edge_pk,
                                                const unsigned char* __restrict__ sup8,
                                                const float* __restrict__ bias,
                                                void* __restrict__ out,
                                                int n_nodes) {
    constexpr int G = D / 16;            // lanes per edge-group
    constexpr int NG = 64 / G;           // edge groups per wave
    constexpr int CH = NG * U;           // edges consumed per iteration
    int node = blockIdx.x * (256 / WAVE) + (threadIdx.x >> 6);
    if (node >= n_nodes) return;
    node = __builtin_amdgcn_readfirstlane(node);
    const int lane = threadIdx.x & 63;
    const int g = lane / G;              // edge-group id
    const int t = lane & (G - 1);        // owns cols [t*16, t*16+16)
    int e = row_ptr[node];
    const int end = row_ptr[node + 1];
    const unsigned char* sup = sup8 + t * 16;

    float acc[16];
#pragma unroll
    for (int i = 0; i < 16; i++) acc[i] = 0.f;

    while (e < end) {
        const int base = e + g * U;
        unsigned int pk[U];
#pragma unroll
        for (int u = 0; u < U; u++) {
            int idx = base + u;
            if (idx > end - 1) idx = end - 1;   // clamp INSIDE row
            pk[u] = edge_pk[idx];
        }
        uintx4 v[U];
#pragma unroll
        for (int u = 0; u < U; u++)
            v[u] = *(const uintx4*)(sup + (size_t)(pk[u] >> 15) * D);
#pragma unroll
        for (int u = 0; u < U; u++) {
            float wq = (float)(pk[u] & 0x7fffu) * (1.f / 32767.f);
            float wt = (base + u < end) ? wq : 0.f;
#pragma unroll
            for (int d = 0; d < 4; d++) {
                floatx2 lo = __builtin_amdgcn_cvt_pk_f32_fp8(v[u][d], false);
                floatx2 hi = __builtin_amdgcn_cvt_pk_f32_fp8(v[u][d], true);
                acc[d * 4 + 0] += lo[0] * wt;
                acc[d * 4 + 1] += lo[1] * wt;
                acc[d * 4 + 2] += hi[0] * wt;
                acc[d * 4 + 3] += hi[1] * wt;
            }
        }
        e += CH;
    }

    // merge edge-groups: butterfly over group-id bits
#pragma unroll
    for (int off = G; off < 64; off <<= 1)
#pragma unroll
        for (int i = 0; i < 16; i++) acc[i] += __shfl_xor(acc[i], off);

    if (!FINAL) {
        if (lane < G) {
            ushort8 o0, o1;
#pragma unroll
            for (int i = 0; i < 8; i++) {
                float r0 = acc[i] + bias[t * 16 + i];
                float r1 = acc[8 + i] + bias[t * 16 + 8 + i];
                r0 = r0 > 0.f ? r0 : 0.f;
                r1 = r1 > 0.f ? r1 : 0.f;
                __hip_bfloat16 b0 = __float2bfloat16(r0);
                __hip_bfloat16 b1 = __float2bfloat16(r1);
                o0[i] = *(unsigned short*)&b0;
                o1[i] = *(unsigned short*)&b1;
            }
            union { ushort8 s; uintx4 u; } c0, c1; c0.s = o0; c1.s = o1;
            unsigned short* op = (unsigned short*)out + (size_t)node * D + t * 16;
            __builtin_nontemporal_store(c0.u, (uintx4*)op);
            __builtin_nontemporal_store(c1.u, (uintx4*)(op + 8));
        }
    } else {
        // D==64 pitch, 40 real classes; fused log_softmax (pad cols excluded;
        // pad support/bias are exactly zero so relu'd pads are 0 but masked).
        float r[16];
#pragma unroll
        for (int i = 0; i < 16; i++) {
            float x = acc[i] + bias[t * 16 + i];
            r[i] = x > 0.f ? x : 0.f;
        }
        float m = -INFINITY;
#pragma unroll
        for (int i = 0; i < 16; i++)
            if (t * 16 + i < 40) m = fmaxf(m, r[i]);
#pragma unroll
        for (int off = 1; off < G; off <<= 1) m = fmaxf(m, __shfl_xor(m, off));
        float s = 0.f;
#pragma unroll
        for (int i = 0; i < 16; i++)
            if (t * 16 + i < 40) s += __expf(r[i] - m);
#pragma unroll
        for (int off = 1; off < G; off <<= 1) s += __shfl_xor(s, off);
        const float lse = __logf(s);
        if (lane < G) {
            float* op = (float*)out + (size_t)node * 40;
#pragma unroll
            for (int i = 0; i < 16; i++) {
                int c = t * 16 + i;
                if (c < 40) op[c] = r[i] - m - lse;
            }
        }
    }
}

// ---------------- launch ----------------------------------------------------

extern "C" void kernel_launch(void* const* d_in, const int* in_sizes, int n_in,
                              void* d_out, int out_size, void* d_ws, size_t ws_size,
                              hipStream_t stream) {
    const float* x    = (const float*)d_in[0];
    const int*   esrc = (const int*)d_in[1];
    const int*   edst = (const int*)d_in[2];
    const float* ew   = (const float*)d_in[3];
    const float* Wm[4] = {(const float*)d_in[4], (const float*)d_in[6],
                          (const float*)d_in[8], (const float*)d_in[10]};
    const float* bm[4] = {(const float*)d_in[5], (const float*)d_in[7],
                          (const float*)d_in[9], (const float*)d_in[11]};
    const int NFEAT = 512;
    const int n_nodes = in_sizes[0] / NFEAT;
    const int n_edges = in_sizes[1];
    float* out = (float*)d_out;

    // --- workspace carve ---
    char* wsp = (char*)d_ws;
    size_t off = 0;
    auto alloc = [&](size_t bytes) -> void* {
        void* p = wsp + off;
        off += (bytes + 255) & ~(size_t)255;
        return p;
    };
    __hip_bfloat16* Sb = (__hip_bfloat16*)alloc((size_t)n_nodes * 256 * sizeof(__hip_bfloat16));
    __hip_bfloat16* Hb = (__hip_bfloat16*)alloc((size_t)n_nodes * 256 * sizeof(__hip_bfloat16));
    __hip_bfloat16* Wt1 = (__hip_bfloat16*)alloc(256 * 512 * sizeof(__hip_bfloat16));
    __hip_bfloat16* Wt2 = (__hip_bfloat16*)alloc(128 * 256 * sizeof(__hip_bfloat16));
    __hip_bfloat16* Wt3 = (__hip_bfloat16*)alloc(64 * 128 * sizeof(__hip_bfloat16));
    __hip_bfloat16* Wt4 = (__hip_bfloat16*)alloc(64 * 64 * sizeof(__hip_bfloat16));
    float* b4p     = (float*)alloc(64 * sizeof(float));
    int*   row_ptr = (int*)alloc(((size_t)n_nodes + 1) * sizeof(int));
    int*   bhist   = (int*)alloc(NBK * sizeof(int));
    int*   bbase   = (int*)alloc((NBK + 1) * sizeof(int));
    int*   gcur    = (int*)alloc(NBK * sizeof(int));
    unsigned int* edge_pk = (unsigned int*)alloc((size_t)n_edges * sizeof(unsigned int));
    // E2 staging (8B/edge) aliases Hb: Hb is first written by L1 SpMM, which
    // runs after phaseB2 completes (same stream) -> safe.
    uint2* E2 = (uint2*)Hb;
    // fp8 supports alias Sb (GEMM writes fp8, spmm reads it, next GEMM
    // overwrites the same region -> sequential, safe).
    unsigned char* Sb8 = (unsigned char*)Sb;
    (void)ws_size;

    // --- weights prep (X is read fp32 directly by GEMM1) ---
    prep_weights_kernel<<<(131072 + 32768 + 8192 + 4096 + 64 + 255) / 256, 256, 0, stream>>>(
        Wm[0], Wm[1], Wm[2], Wm[3], bm[3], Wt1, Wt2, Wt3, Wt4, b4p);

    // --- CSR build (bucket-local) ---
    hipMemsetAsync(bhist, 0, NBK * sizeof(int), stream);
    int hblocks = (n_edges + CHA - 1) / CHA;
    bucket_hist<<<hblocks, 256, 0, stream>>>(edst, n_edges, bhist);
    bucket_scan<<<1, NBK, 0, stream>>>(bhist, bbase, gcur);
    scatter_phaseA<<<hblocks, 256, 0, stream>>>(esrc, edst, ew, n_edges, gcur, E2);
    scatter_phaseB2<<<NBK, 256, 0, stream>>>(E2, bbase, n_nodes, n_edges,
                                             row_ptr, edge_pk);

    // --- layers ---
    int spmm_blocks = (n_nodes + 3) / 4;
    dim3 gg1(256 / 128, (n_nodes + 127) / 128);   // 128x128 tiles
    dim3 gg2(128 / 128, (n_nodes + 127) / 128);
    dim3 g3(64 / 64, (n_nodes + 127) / 128);      // 128x64 tiles

    // L1: 512 -> 256 (A = fp32 X direct; support fp8 e4m3)
    gemm128<1, 1><<<gg1, 256, 0, stream>>>(x, Wt1, Sb8, n_nodes, 512, 256);
    spmm_fp8<256, 4, false><<<spmm_blocks, 256, 0, stream>>>(
        row_ptr, edge_pk, Sb8, bm[0], Hb, n_nodes);
    // L2: 256 -> 128 (support fp8 e4m3)
    gemm128<0, 1><<<gg2, 256, 0, stream>>>(Hb, Wt2, Sb8, n_nodes, 256, 128);
    spmm_fp8<128, 2, false><<<spmm_blocks, 256, 0, stream>>>(
        row_ptr, edge_pk, Sb8, bm[1], Hb, n_nodes);
    // L3: 128 -> 64 (support fp8 e4m3)
    gemm_bf16<1><<<g3, 256, 0, stream>>>(Hb, Wt3, Sb8, n_nodes, 128, 64);
    spmm_fp8<64, 1, false><<<spmm_blocks, 256, 0, stream>>>(
        row_ptr, edge_pk, Sb8, bm[2], Hb, n_nodes);
    // L4: 64 -> 40 (N padded to 64; support fp8 e4m3; fused log_softmax
    // writes final fp32 [n,40] directly)
    gemm_bf16<1><<<g3, 256, 0, stream>>>(Hb, Wt4, Sb8, n_nodes, 64, 64);
    spmm_fp8<64, 1, true><<<spmm_blocks, 256, 0, stream>>>(
        row_ptr, edge_pk, Sb8, b4p, out, n_nodes);
}